// Round 13
// baseline (210.878 us; speedup 1.0000x reference)
//
#include <hip/hip_runtime.h>
#include <hip/hip_bf16.h>
#include <math.h>

#define NH 16
#define S_LEN 1024
#define DK 64
#define D_MODEL 1024
#define HSZ 8388608          // B*NH*S*DK elements per q/k/v buffer

typedef __attribute__((ext_vector_type(8))) short bf16x8;
typedef __attribute__((ext_vector_type(4))) float f32x4;
typedef unsigned short USH;

#define EXPSCALE 0.1803368801111204f   // 0.125 * log2(e)

__device__ __forceinline__ float fast_exp2(float x) {
    return __builtin_amdgcn_exp2f(x);
}

__device__ __forceinline__ short f2b(float x) {
    union { __hip_bfloat16 h; short s; } u;
    u.h = __float2bfloat16(x);
    return u.s;
}
__device__ __forceinline__ float b2f(USH u) {
    union { unsigned i; float f; } x;
    x.i = (unsigned)u << 16;
    return x.f;
}

__device__ __forceinline__ void gload16(const void* src, void* lds) {
    __builtin_amdgcn_global_load_lds(
        (const __attribute__((address_space(1))) void*)src,
        (__attribute__((address_space(3))) void*)lds,
        16, 0, 0);
}

// ---------------------------------------------------------------------------
// fp32 -> bf16 conversion (exact-grid, 8 elems/thread)
// ---------------------------------------------------------------------------
__global__ __launch_bounds__(256)
void conv_bf16_kernel(const float* __restrict__ in, USH* __restrict__ out) {
    const int i = (blockIdx.x * 256 + threadIdx.x) * 8;
    const float4 a = *(const float4*)&in[i];
    const float4 b = *(const float4*)&in[i + 4];
    ushort4 o0, o1;
    o0.x = (USH)f2b(a.x); o0.y = (USH)f2b(a.y); o0.z = (USH)f2b(a.z); o0.w = (USH)f2b(a.w);
    o1.x = (USH)f2b(b.x); o1.y = (USH)f2b(b.y); o1.z = (USH)f2b(b.z); o1.w = (USH)f2b(b.w);
    *(ushort4*)&out[i] = o0;
    *(ushort4*)&out[i + 4] = o1;
}

// ---------------------------------------------------------------------------
// Transpose + convert: in [R][C] fp32 -> out [C][R] bf16. 64x64 tiles.
// ---------------------------------------------------------------------------
__global__ __launch_bounds__(256)
void transp_bf16_kernel(const float* __restrict__ in, USH* __restrict__ out,
                        int R, int C) {
    __shared__ USH Ts[64][65];
    const int r0 = blockIdx.y * 64, c0 = blockIdx.x * 64;
    const int tr = threadIdx.x >> 4;
    const int tc4 = (threadIdx.x & 15) * 4;
    #pragma unroll
    for (int ph = 0; ph < 4; ++ph) {
        const int r = ph * 16 + tr;
        const float4 v = *(const float4*)&in[(size_t)(r0 + r) * C + c0 + tc4];
        Ts[tc4 + 0][r] = (USH)f2b(v.x);
        Ts[tc4 + 1][r] = (USH)f2b(v.y);
        Ts[tc4 + 2][r] = (USH)f2b(v.z);
        Ts[tc4 + 3][r] = (USH)f2b(v.w);
    }
    __syncthreads();
    #pragma unroll
    for (int ph = 0; ph < 4; ++ph) {
        const int cc = ph * 16 + tr;
        ushort4 o;
        o.x = Ts[cc][tc4 + 0]; o.y = Ts[cc][tc4 + 1];
        o.z = Ts[cc][tc4 + 2]; o.w = Ts[cc][tc4 + 3];
        *(ushort4*)&out[(size_t)(c0 + cc) * R + r0 + tc4] = o;
    }
}

// ---------------------------------------------------------------------------
// Per-head V transpose (bf16): in [bh][s][64] -> out [bh][d=64][s=1024]
// ---------------------------------------------------------------------------
__global__ __launch_bounds__(256)
void vtransp_kernel(const USH* __restrict__ in, USH* __restrict__ out) {
    __shared__ USH T[64][72];
    const int bh = blockIdx.x >> 4;
    const int s0 = (blockIdx.x & 15) * 64;
    const int r = threadIdx.x >> 4;
    const int c4 = (threadIdx.x & 15) * 4;
    #pragma unroll
    for (int ph = 0; ph < 4; ++ph) {
        const int row = ph * 16 + r;   // s offset
        const ushort4 v = *(const ushort4*)
            &in[((size_t)bh * S_LEN + s0 + row) * DK + c4];
        T[row][c4 + 0] = v.x; T[row][c4 + 1] = v.y;
        T[row][c4 + 2] = v.z; T[row][c4 + 3] = v.w;
    }
    __syncthreads();
    #pragma unroll
    for (int ph = 0; ph < 4; ++ph) {
        const int d = ph * 16 + r;
        ushort4 o;
        o.x = T[c4 + 0][d]; o.y = T[c4 + 1][d];
        o.z = T[c4 + 2][d]; o.w = T[c4 + 3][d];
        *(ushort4*)&out[(size_t)bh * (S_LEN * DK) + (size_t)d * S_LEN + s0 + c4] = o;
    }
}

// ---------------------------------------------------------------------------
// bf16 MFMA GEMM (m97 structure) — q/k/v written bf16 when QKV=1,
// all row-major coalesced (V transposed by separate kernel).
// ---------------------------------------------------------------------------
template<int QKV>
__global__ __launch_bounds__(256)
void mfma_gemm_kernel(const USH* __restrict__ A, const USH* __restrict__ Bt,
                      const float* __restrict__ bias,
                      float* __restrict__ Cf, USH* __restrict__ Cq,
                      USH* __restrict__ Ck, USH* __restrict__ Cv,
                      int M, int N, int K) {
    __shared__ __align__(16) USH As[128 * 32];
    __shared__ __align__(16) USH Bs[128 * 32];
    const int t = threadIdx.x;
    const int w = t >> 6, lane = t & 63, g = lane >> 4, c = lane & 15;
    const int wm = w >> 1, wn = w & 1;
    const int bm0 = blockIdx.y * 128, bn0 = blockIdx.x * 128;

    const int sk = ((t & 3) ^ ((t >> 3) & 3)) * 8;
    const USH* pa0 = A + (size_t)(bm0 + (t >> 2)) * K + sk;
    const USH* pa1 = pa0 + (size_t)64 * K;
    const USH* pb0 = Bt + (size_t)(bn0 + (t >> 2)) * K + sk;
    const USH* pb1 = pb0 + (size_t)64 * K;
    USH* ldsA0 = &As[(t & ~63) * 8];
    USH* ldsA1 = ldsA0 + 2048;
    USH* ldsB0 = &Bs[(t & ~63) * 8];
    USH* ldsB1 = ldsB0 + 2048;

    unsigned aoff[4], boff[4];
    #pragma unroll
    for (int i = 0; i < 4; ++i) {
        const int r = wm * 64 + i * 16 + c;
        aoff[i] = ((unsigned)(r * 64 + g * 16)) ^ ((((unsigned)r >> 1) & 3) << 4);
        const int n = wn * 64 + i * 16 + c;
        boff[i] = ((unsigned)(n * 64 + g * 16)) ^ ((((unsigned)n >> 1) & 3) << 4);
    }

    f32x4 acc[4][4];
    #pragma unroll
    for (int i = 0; i < 4; ++i)
        #pragma unroll
        for (int j = 0; j < 4; ++j) acc[i][j] = (f32x4)0.f;

    for (int k0 = 0; k0 < K; k0 += 32) {
        gload16(pa0 + k0, ldsA0);
        gload16(pa1 + k0, ldsA1);
        gload16(pb0 + k0, ldsB0);
        gload16(pb1 + k0, ldsB1);
        __syncthreads();

        bf16x8 af[4], bfr[4];
        #pragma unroll
        for (int i = 0; i < 4; ++i) af[i] = *(const bf16x8*)((const char*)As + aoff[i]);
        #pragma unroll
        for (int j = 0; j < 4; ++j) bfr[j] = *(const bf16x8*)((const char*)Bs + boff[j]);
        #pragma unroll
        for (int i = 0; i < 4; ++i)
            #pragma unroll
            for (int j = 0; j < 4; ++j)
                acc[i][j] = __builtin_amdgcn_mfma_f32_16x16x32_bf16(
                    af[i], bfr[j], acc[i][j], 0, 0, 0);
        __syncthreads();
    }

    #pragma unroll
    for (int i = 0; i < 4; ++i) {
        #pragma unroll
        for (int reg = 0; reg < 4; ++reg) {
            const int m = bm0 + wm * 64 + i * 16 + g * 4 + reg;
            #pragma unroll
            for (int j = 0; j < 4; ++j) {
                const int n = bn0 + wn * 64 + j * 16 + c;
                const float v = acc[i][j][reg] + bias[n];
                if (QKV) {
                    const int which = n >> 10;
                    const int h = (n & 1023) >> 6, d = n & 63;
                    const int b = m >> 10, s = m & 1023;
                    const size_t idx = (((size_t)(b * NH + h)) * S_LEN + s) * DK + d;
                    if (which == 0)      Cq[idx] = (USH)f2b(v);
                    else if (which == 1) Ck[idx] = (USH)f2b(v);
                    else                 Cv[idx] = (USH)f2b(v);
                } else {
                    Cf[(size_t)m * N + n] = v;
                }
            }
        }
    }
}

// ---------------------------------------------------------------------------
// MFMA flash attention: 8 waves x 128 q-rows per block, KVBLK=64, dbuf async
// staging. Fixed-shift softmax; per-lane partial sums reduced in epilogue.
// LDS trimmed to 52352 B -> 3 blocks/CU:
//   0      ktb0  8K        (phase0: staged tile-0 K)
//   8192   ktb1  8K        (phase0 alias: lutkb 4K)
//   16384  vtb0  8K        (phase0: staged tile-0 V)
//   24576  vtb1  8K
//   32768  pb    8K  (8 waves x 1KB, [16][32] bf16, chunk ^= (row&3);
//                     key-halves time-share the buffer — same-wave DS order)
//   40960  qrelb bf16 [128][20]  5120
//   46080  lvfb  bf16 [17][64]   2176
//   48256  tapss bf16 [128][16]  4096
// phase0 alias: qsb [128][64] swz = 32768..49152 (over pb/qrelb/lvfb/tapss);
// extra barrier separates all qsb reads from overlay writes.
// ---------------------------------------------------------------------------
__global__ __launch_bounds__(512, 4)
void attn_mfma_kernel(const USH* __restrict__ qb,
                      const USH* __restrict__ kbuf,
                      const USH* __restrict__ vtg,
                      const float* __restrict__ lut_k,
                      const float* __restrict__ lut_v,
                      USH* __restrict__ ao) {
    const int bid = blockIdx.x;
    const int logical = (bid & 7) * 128 + (bid >> 3);   // XCD-contiguous bh
    const int ib = 7 - (logical & 7);                   // LPT: big ib first
    const int bh = logical >> 3;
    const int b = bh >> 4, h = bh & 15;
    const int i0 = ib * 128;
    const int t = threadIdx.x;
    const int w = t >> 6;          // 0..7
    const int lane = t & 63;
    const int g = lane >> 4;
    const int c = lane & 15;

    __shared__ __align__(16) char smem[52352];
    char* pb     = smem + 32768;             // P buffers (main loop)
    char* qsb    = smem + 32768;             // phase0 alias: q [128][64] swz
    char* lutkb  = smem + 8192;              // phase0 alias of ktb1
    USH* qrelb   = (USH*)(smem + 40960);     // [128][20] bf16
    USH* lvfb    = (USH*)(smem + 46080);     // [17][64] bf16
    USH* tapssb  = (USH*)(smem + 48256);     // [128][16] bf16 p values

    const USH* qp  = qb   + (size_t)bh * (S_LEN * DK);
    const USH* kp  = kbuf + (size_t)bh * (S_LEN * DK);
    const USH* vtp = vtg  + (size_t)bh * (S_LEN * DK);  // [d=64][s=1024]

    // async stage of one 64x64 K tile + V^T tile (512 thr = 1 gload16 each)
    auto stage = [&](int j0, int koff, int voff) {
        const int o = t * 16;
        const int row = o >> 7;
        const int chunk = (o >> 4) & 7;
        const int sc = (chunk ^ (row & 7)) * 8;
        gload16(kp + (size_t)(j0 + row) * DK + sc, smem + koff + o);
        gload16(vtp + (size_t)row * S_LEN + j0 + sc, smem + voff + o);
    };

    // ---- phase 0: issue tile-0 loads; stage q (swz) + lut_k; lut_v to regs
    stage(0, 0, 16384);
    for (int f = t; f < 2048; f += 512) {
        const int row = f >> 4, c4 = (f & 15) * 4;
        unsigned byte = ((unsigned)(row * 128 + c4 * 2)) ^ (((unsigned)row & 7) << 4);
        *(ushort4*)(qsb + byte) = *(const ushort4*)&qp[(size_t)(i0 + row) * DK + c4];
    }
    // lut_k -> bf16 LDS [32][64], rows 17..31 zero, swizzled (in ktb1)
    for (int e = t; e < 32 * 64; e += 512) {
        const int row = e >> 6, d = e & 63;
        const USH v = (row < 17) ? (USH)f2b(lut_k[row * 64 + d]) : (USH)0;
        unsigned byte = ((unsigned)(row * 128 + d * 2)) ^ (((unsigned)row & 7) << 4);
        *(USH*)(lutkb + byte) = v;
    }
    const float lv0f = lut_v[t];
    const float lv1f = lut_v[t + 512];
    const float lv2f = (t + 1024 < 1088) ? lut_v[t + 1024] : 0.f;
    __syncthreads();   // drains tile-0 gloads; qsb/lutkb visible

    // Q fragments from swizzled bf16 LDS (wave w owns rows w*16..+15)
    bf16x8 qa[2];
    {
        const int row = w * 16 + c;
        #pragma unroll
        for (int kh = 0; kh < 2; ++kh) {
            unsigned byte = ((unsigned)(row * 128 + kh * 64 + g * 16))
                          ^ (((unsigned)row & 7) << 4);
            qa[kh] = *(const bf16x8*)(qsb + byte);
        }
    }

    // qrel via MFMA: lut_k rows as 17 virtual keys (results to regs)
    f32x4 qr[2];
    qr[0] = (f32x4)0.f; qr[1] = (f32x4)0.f;
    #pragma unroll
    for (int sub2 = 0; sub2 < 2; ++sub2) {
        const int tap = sub2 * 16 + c;
        #pragma unroll
        for (int kh = 0; kh < 2; ++kh) {
            unsigned byte = ((unsigned)(tap * 128 + kh * 64 + g * 16))
                          ^ (((unsigned)tap & 7) << 4);
            bf16x8 lb = *(const bf16x8*)(lutkb + byte);
            qr[sub2] = __builtin_amdgcn_mfma_f32_16x16x32_bf16(
                qa[kh], lb, qr[sub2], 0, 0, 0);
        }
    }
    __syncthreads();   // ALL qsb/lutkb reads complete; overlay now writable

    // write qrelb + lvfb (overlay region)
    #pragma unroll
    for (int sub2 = 0; sub2 < 2; ++sub2) {
        const int tap = sub2 * 16 + c;
        if (tap < 17) {
            #pragma unroll
            for (int r = 0; r < 4; ++r)
                qrelb[(w * 16 + g * 4 + r) * 20 + tap] = (USH)f2b(qr[sub2][r]);
        }
    }
    lvfb[t] = (USH)f2b(lv0f);
    lvfb[t + 512] = (USH)f2b(lv1f);
    if (t + 1024 < 1088) lvfb[t + 1024] = (USH)f2b(lv2f);

    // hoist tap-0 qrel (own-wave region; same-wave DS order, no barrier)
    float qrel0s[4];
    #pragma unroll
    for (int r = 0; r < 4; ++r)
        qrel0s[r] = b2f(qrelb[(w * 16 + g * 4 + r) * 20]) * EXPSCALE;

    f32x4 acc[4];
    #pragma unroll
    for (int dt = 0; dt < 4; ++dt) acc[dt] = (f32x4)0.f;
    float l_r[4];   // per-lane PARTIAL row sums (reduced in epilogue)
    #pragma unroll
    for (int r = 0; r < 4; ++r) l_r[r] = 0.f;

    const int wrow0 = i0 + w * 16;   // first q-row owned by this wave
    const int NT = 2 * ib + 2;
    for (int tile = 0; tile < NT; ++tile) {
        const int cur = tile & 1;
        if (tile + 1 < NT)
            stage((tile + 1) << 6, cur ? 0 : 8192, cur ? 16384 : 24576);

        // ---- per-wave fully-masked skip (wave-uniform condition) ----
        if (tile * 64 > wrow0 + 15) {
            __syncthreads();
            continue;
        }

        const char* ktb = smem + (cur ? 8192 : 0);
        const char* vtb = smem + (cur ? 24576 : 16384);

        // ---- QK^T ----
        float p[4][4];
        __builtin_amdgcn_s_setprio(1);
        f32x4 s[4];
        #pragma unroll
        for (int sub = 0; sub < 4; ++sub) {
            s[sub] = (f32x4)0.f;
            const int krow = sub * 16 + c;
            #pragma unroll
            for (int kh = 0; kh < 2; ++kh) {
                unsigned byte = ((unsigned)krow << 7) + ((unsigned)kh << 6) + ((unsigned)g << 4);
                byte ^= (unsigned)(krow & 7) << 4;
                bf16x8 kb = *(const bf16x8*)(ktb + byte);
                s[sub] = __builtin_amdgcn_mfma_f32_16x16x32_bf16(qa[kh], kb, s[sub], 0, 0, 0);
            }
        }
        __builtin_amdgcn_s_setprio(0);

        if (tile * 64 + 79 <= wrow0) {
            // ---- per-wave interior: dj <= -16 -> tap index 0 everywhere ----
            #pragma unroll
            for (int sub = 0; sub < 4; ++sub)
                #pragma unroll
                for (int r = 0; r < 4; ++r)
                    p[sub][r] = fast_exp2(s[sub][r] * EXPSCALE + qrel0s[r]);
        } else {
            // ---- boundary: clamped tap lookup + causal mask + tap capture ----
            #pragma unroll
            for (int sub = 0; sub < 4; ++sub) {
                const int dbase = tile * 64 + (sub * 16 + c) - i0 - (w * 16 + g * 4);
                #pragma unroll
                for (int r = 0; r < 4; ++r) {
                    const int dj = dbase - r;
                    int t17 = dj + 16;
                    t17 = t17 < 0 ? 0 : (t17 > 16 ? 16 : t17);
                    const int il = w * 16 + g * 4 + r;
                    float pv = fast_exp2((s[sub][r] + b2f(qrelb[il * 20 + t17])) * EXPSCALE);
                    if (dj > 0) pv = 0.f;
                    p[sub][r] = pv;
                    if (dj >= -15 && dj <= 0)
                        tapssb[il * 16 + dj + 15] = (USH)f2b(pv);
                }
            }
        }

        // ---- accumulate per-lane partial row sums ----
        #pragma unroll
        for (int r = 0; r < 4; ++r)
            l_r[r] += (p[0][r] + p[1][r]) + (p[2][r] + p[3][r]);

        // ---- PV via time-shared 1KB per-wave P buffer ([16][32] bf16) ----
        char* pw = pb + w * 1024;
        #pragma unroll
        for (int half = 0; half < 2; ++half) {
            // write this key-half (same-wave DS ordering makes reuse safe)
            #pragma unroll
            for (int sh = 0; sh < 2; ++sh) {
                const int sub = half * 2 + sh;
                #pragma unroll
                for (int r = 0; r < 4; ++r) {
                    const int row = g * 4 + r;
                    unsigned byte = (unsigned)(row * 64 + (sh * 16 + c) * 2);
                    byte ^= (unsigned)(row & 3) << 4;
                    *(short*)(pw + byte) = f2b(p[sub][r]);
                }
            }
            unsigned pbyte = ((unsigned)c * 64 + (unsigned)g * 16)
                           ^ (((unsigned)c & 3) << 4);
            bf16x8 pa = *(const bf16x8*)(pw + pbyte);
            __builtin_amdgcn_s_setprio(1);
            #pragma unroll
            for (int dt = 0; dt < 4; ++dt) {
                const int d = dt * 16 + c;
                unsigned vbyte = ((unsigned)d << 7) + ((unsigned)half << 6) + ((unsigned)g << 4);
                vbyte ^= (unsigned)(d & 7) << 4;
                bf16x8 vb = *(const bf16x8*)(vtb + vbyte);
                acc[dt] = __builtin_amdgcn_mfma_f32_16x16x32_bf16(pa, vb, acc[dt], 0, 0, 0);
            }
            __builtin_amdgcn_s_setprio(0);
        }
        __syncthreads();
    }

    // ---- epilogue: reduce row sums, taps + bin-0 residual, write ----
    const int rbase = w * 16 + g * 4;
    #pragma unroll
    for (int r = 0; r < 4; ++r) {
        float lsum = l_r[r];
        #pragma unroll
        for (int msk = 1; msk < 16; msk <<= 1)
            lsum += __shfl_xor(lsum, msk);
        const int il = rbase + r;
        float c0 = lsum;
        float tp[16];
        #pragma unroll
        for (int tap = 0; tap < 16; ++tap) {
            const int jg = i0 + il + tap - 15;
            const float pv = (jg >= 0) ? b2f(tapssb[il * 16 + tap]) : 0.f;
            tp[tap] = pv;
            c0 -= pv;
        }
        const float invl = 1.f / lsum;
        #pragma unroll
        for (int dt = 0; dt < 4; ++dt) {
            const int d = dt * 16 + c;
            float o = acc[dt][r] + c0 * b2f(lvfb[d]);
            #pragma unroll
            for (int tap = 0; tap < 16; ++tap)
                o += tp[tap] * b2f(lvfb[(tap + 1) * 64 + d]);
            o *= invl;
            ao[((size_t)b * S_LEN + (i0 + il)) * D_MODEL + h * DK + d] = (USH)f2b(o);
        }
    }
}

// ---------------------------------------------------------------------------
extern "C" void kernel_launch(void* const* d_in, const int* in_sizes, int n_in,
                              void* d_out, int out_size, void* d_ws, size_t ws_size,
                              hipStream_t stream) {
    const float* x      = (const float*)d_in[0];
    const float* W_attn = (const float*)d_in[1];
    const float* b_attn = (const float*)d_in[2];
    const float* W_proj = (const float*)d_in[3];
    const float* b_proj = (const float*)d_in[4];
    const float* lut_k  = (const float*)d_in[5];
    const float* lut_v  = (const float*)d_in[6];
    float* out = (float*)d_out;

    // workspace layout (all USH)
    USH* qb    = (USH*)d_ws;            // 8M
    USH* kb    = qb + HSZ;              // 8M
    USH* vb    = kb + HSZ;              // 8M (row-major V)
    USH* vtg   = vb + HSZ;              // 8M (per-head transposed V)
    USH* aob   = vtg + HSZ;             // 8M
    USH* xb    = aob + HSZ;             // 8M
    USH* watt  = xb + HSZ;              // 3M
    USH* wproj = watt + 3145728;        // 1M

    // 0) conversions
    conv_bf16_kernel<<<HSZ / (256 * 8), 256, 0, stream>>>(x, xb);
    transp_bf16_kernel<<<dim3(3072 / 64, 1024 / 64), 256, 0, stream>>>(
        W_attn, watt, 1024, 3072);
    transp_bf16_kernel<<<dim3(1024 / 64, 1024 / 64), 256, 0, stream>>>(
        W_proj, wproj, 1024, 1024);

    // 1) QKV projection (bf16 MFMA), coalesced row-major outputs
    mfma_gemm_kernel<1><<<dim3(3072 / 128, 8192 / 128), 256, 0, stream>>>(
        xb, watt, b_attn, nullptr, qb, kb, vb, 8192, 3072, 1024);

    // 1b) per-head V transpose (coalesced LDS-tile kernel, ~6 us)
    vtransp_kernel<<<2048, 256, 0, stream>>>(vb, vtg);

    // 2) attention (8 waves x 128 q-rows, 3 blocks/CU)
    attn_mfma_kernel<<<1024, 512, 0, stream>>>(qb, kb, vtg, lut_k, lut_v, aob);

    // 3) output projection (bf16 MFMA)
    mfma_gemm_kernel<0><<<dim3(1024 / 128, 8192 / 128), 256, 0, stream>>>(
        aob, wproj, b_proj, out, nullptr, nullptr, nullptr, 8192, 1024, 1024);
}

// Round 14
// 207.990 us; speedup vs baseline: 1.0139x; 1.0139x over previous
//
#include <hip/hip_runtime.h>
#include <hip/hip_bf16.h>
#include <math.h>

#define NH 16
#define S_LEN 1024
#define DK 64
#define D_MODEL 1024
#define HSZ 8388608          // B*NH*S*DK elements per q/k/v buffer

typedef __attribute__((ext_vector_type(8))) short bf16x8;
typedef __attribute__((ext_vector_type(4))) float f32x4;
typedef unsigned short USH;

#define EXPSCALE 0.1803368801111204f   // 0.125 * log2(e)

__device__ __forceinline__ float fast_exp2(float x) {
    return __builtin_amdgcn_exp2f(x);
}

__device__ __forceinline__ short f2b(float x) {
    union { __hip_bfloat16 h; short s; } u;
    u.h = __float2bfloat16(x);
    return u.s;
}
__device__ __forceinline__ float b2f(USH u) {
    union { unsigned i; float f; } x;
    x.i = (unsigned)u << 16;
    return x.f;
}

__device__ __forceinline__ void gload16(const void* src, void* lds) {
    __builtin_amdgcn_global_load_lds(
        (const __attribute__((address_space(1))) void*)src,
        (__attribute__((address_space(3))) void*)lds,
        16, 0, 0);
}

// ---------------------------------------------------------------------------
// fp32 -> bf16 conversion (exact-grid, 8 elems/thread)
// ---------------------------------------------------------------------------
__global__ __launch_bounds__(256)
void conv_bf16_kernel(const float* __restrict__ in, USH* __restrict__ out) {
    const int i = (blockIdx.x * 256 + threadIdx.x) * 8;
    const float4 a = *(const float4*)&in[i];
    const float4 b = *(const float4*)&in[i + 4];
    ushort4 o0, o1;
    o0.x = (USH)f2b(a.x); o0.y = (USH)f2b(a.y); o0.z = (USH)f2b(a.z); o0.w = (USH)f2b(a.w);
    o1.x = (USH)f2b(b.x); o1.y = (USH)f2b(b.y); o1.z = (USH)f2b(b.z); o1.w = (USH)f2b(b.w);
    *(ushort4*)&out[i] = o0;
    *(ushort4*)&out[i + 4] = o1;
}

// ---------------------------------------------------------------------------
// Transpose + convert: in [R][C] fp32 -> out [C][R] bf16. 64x64 tiles.
// ---------------------------------------------------------------------------
__global__ __launch_bounds__(256)
void transp_bf16_kernel(const float* __restrict__ in, USH* __restrict__ out,
                        int R, int C) {
    __shared__ USH Ts[64][65];
    const int r0 = blockIdx.y * 64, c0 = blockIdx.x * 64;
    const int tr = threadIdx.x >> 4;
    const int tc4 = (threadIdx.x & 15) * 4;
    #pragma unroll
    for (int ph = 0; ph < 4; ++ph) {
        const int r = ph * 16 + tr;
        const float4 v = *(const float4*)&in[(size_t)(r0 + r) * C + c0 + tc4];
        Ts[tc4 + 0][r] = (USH)f2b(v.x);
        Ts[tc4 + 1][r] = (USH)f2b(v.y);
        Ts[tc4 + 2][r] = (USH)f2b(v.z);
        Ts[tc4 + 3][r] = (USH)f2b(v.w);
    }
    __syncthreads();
    #pragma unroll
    for (int ph = 0; ph < 4; ++ph) {
        const int cc = ph * 16 + tr;
        ushort4 o;
        o.x = Ts[cc][tc4 + 0]; o.y = Ts[cc][tc4 + 1];
        o.z = Ts[cc][tc4 + 2]; o.w = Ts[cc][tc4 + 3];
        *(ushort4*)&out[(size_t)(c0 + cc) * R + r0 + tc4] = o;
    }
}

// ---------------------------------------------------------------------------
// Per-head V transpose (bf16): in [bh][s][64] -> out [bh][d=64][s=1024]
// ---------------------------------------------------------------------------
__global__ __launch_bounds__(256)
void vtransp_kernel(const USH* __restrict__ in, USH* __restrict__ out) {
    __shared__ USH T[64][72];
    const int bh = blockIdx.x >> 4;
    const int s0 = (blockIdx.x & 15) * 64;
    const int r = threadIdx.x >> 4;
    const int c4 = (threadIdx.x & 15) * 4;
    #pragma unroll
    for (int ph = 0; ph < 4; ++ph) {
        const int row = ph * 16 + r;   // s offset
        const ushort4 v = *(const ushort4*)
            &in[((size_t)bh * S_LEN + s0 + row) * DK + c4];
        T[row][c4 + 0] = v.x; T[row][c4 + 1] = v.y;
        T[row][c4 + 2] = v.z; T[row][c4 + 3] = v.w;
    }
    __syncthreads();
    #pragma unroll
    for (int ph = 0; ph < 4; ++ph) {
        const int d = ph * 16 + r;
        ushort4 o;
        o.x = T[c4 + 0][d]; o.y = T[c4 + 1][d];
        o.z = T[c4 + 2][d]; o.w = T[c4 + 3][d];
        *(ushort4*)&out[(size_t)bh * (S_LEN * DK) + (size_t)d * S_LEN + s0 + c4] = o;
    }
}

// ---------------------------------------------------------------------------
// bf16 MFMA GEMM (m97 structure) — q/k/v written bf16 when QKV=1,
// all row-major coalesced (V transposed by separate kernel).
// ---------------------------------------------------------------------------
template<int QKV>
__global__ __launch_bounds__(256)
void mfma_gemm_kernel(const USH* __restrict__ A, const USH* __restrict__ Bt,
                      const float* __restrict__ bias,
                      float* __restrict__ Cf, USH* __restrict__ Cq,
                      USH* __restrict__ Ck, USH* __restrict__ Cv,
                      int M, int N, int K) {
    __shared__ __align__(16) USH As[128 * 32];
    __shared__ __align__(16) USH Bs[128 * 32];
    const int t = threadIdx.x;
    const int w = t >> 6, lane = t & 63, g = lane >> 4, c = lane & 15;
    const int wm = w >> 1, wn = w & 1;
    const int bm0 = blockIdx.y * 128, bn0 = blockIdx.x * 128;

    const int sk = ((t & 3) ^ ((t >> 3) & 3)) * 8;
    const USH* pa0 = A + (size_t)(bm0 + (t >> 2)) * K + sk;
    const USH* pa1 = pa0 + (size_t)64 * K;
    const USH* pb0 = Bt + (size_t)(bn0 + (t >> 2)) * K + sk;
    const USH* pb1 = pb0 + (size_t)64 * K;
    USH* ldsA0 = &As[(t & ~63) * 8];
    USH* ldsA1 = ldsA0 + 2048;
    USH* ldsB0 = &Bs[(t & ~63) * 8];
    USH* ldsB1 = ldsB0 + 2048;

    unsigned aoff[4], boff[4];
    #pragma unroll
    for (int i = 0; i < 4; ++i) {
        const int r = wm * 64 + i * 16 + c;
        aoff[i] = ((unsigned)(r * 64 + g * 16)) ^ ((((unsigned)r >> 1) & 3) << 4);
        const int n = wn * 64 + i * 16 + c;
        boff[i] = ((unsigned)(n * 64 + g * 16)) ^ ((((unsigned)n >> 1) & 3) << 4);
    }

    f32x4 acc[4][4];
    #pragma unroll
    for (int i = 0; i < 4; ++i)
        #pragma unroll
        for (int j = 0; j < 4; ++j) acc[i][j] = (f32x4)0.f;

    for (int k0 = 0; k0 < K; k0 += 32) {
        gload16(pa0 + k0, ldsA0);
        gload16(pa1 + k0, ldsA1);
        gload16(pb0 + k0, ldsB0);
        gload16(pb1 + k0, ldsB1);
        __syncthreads();

        bf16x8 af[4], bfr[4];
        #pragma unroll
        for (int i = 0; i < 4; ++i) af[i] = *(const bf16x8*)((const char*)As + aoff[i]);
        #pragma unroll
        for (int j = 0; j < 4; ++j) bfr[j] = *(const bf16x8*)((const char*)Bs + boff[j]);
        #pragma unroll
        for (int i = 0; i < 4; ++i)
            #pragma unroll
            for (int j = 0; j < 4; ++j)
                acc[i][j] = __builtin_amdgcn_mfma_f32_16x16x32_bf16(
                    af[i], bfr[j], acc[i][j], 0, 0, 0);
        __syncthreads();
    }

    #pragma unroll
    for (int i = 0; i < 4; ++i) {
        #pragma unroll
        for (int reg = 0; reg < 4; ++reg) {
            const int m = bm0 + wm * 64 + i * 16 + g * 4 + reg;
            #pragma unroll
            for (int j = 0; j < 4; ++j) {
                const int n = bn0 + wn * 64 + j * 16 + c;
                const float v = acc[i][j][reg] + bias[n];
                if (QKV) {
                    const int which = n >> 10;
                    const int h = (n & 1023) >> 6, d = n & 63;
                    const int b = m >> 10, s = m & 1023;
                    const size_t idx = (((size_t)(b * NH + h)) * S_LEN + s) * DK + d;
                    if (which == 0)      Cq[idx] = (USH)f2b(v);
                    else if (which == 1) Ck[idx] = (USH)f2b(v);
                    else                 Cv[idx] = (USH)f2b(v);
                } else {
                    Cf[(size_t)m * N + n] = v;
                }
            }
        }
    }
}

// ---------------------------------------------------------------------------
// MFMA flash attention: 8 waves x 128 q-rows per block, KVBLK=64.
// TRI-BUFFERED counted-vmcnt pipeline (T4): stage issued 2 tiles ahead;
// end-of-iter s_waitcnt vmcnt(2) + raw s_barrier — next-next tile's loads
// stay in flight across the barrier (never drain to 0 in the loop).
// Fixed-shift softmax; per-lane partial sums reduced in epilogue.
// LDS map (76928 B -> 2 blocks/CU):
//   0      ktb0  8K   8192 ktb1 8K (ph0 alias: lutkb 4K)   16384 ktb2 8K
//   24576  vtb0  8K   32768 vtb1 8K   40960 vtb2 8K
//   49152  pb    16K (8 waves x 2KB [16][64] bf16, ^(row&7)<<4)
//                 (ph0 alias: qsb [128][64] swz)
//   65536  qrelb bf16 [128][20]  5120
//   70656  lvfb  bf16 [17][64]   2176
//   72832  tapss bf16 [128][16]  4096
// ---------------------------------------------------------------------------
__global__ __launch_bounds__(512, 4)
void attn_mfma_kernel(const USH* __restrict__ qb,
                      const USH* __restrict__ kbuf,
                      const USH* __restrict__ vtg,
                      const float* __restrict__ lut_k,
                      const float* __restrict__ lut_v,
                      USH* __restrict__ ao) {
    const int bid = blockIdx.x;
    const int logical = (bid & 7) * 128 + (bid >> 3);   // XCD-contiguous bh
    const int ib = 7 - (logical & 7);                   // LPT: big ib first
    const int bh = logical >> 3;
    const int b = bh >> 4, h = bh & 15;
    const int i0 = ib * 128;
    const int t = threadIdx.x;
    const int w = t >> 6;          // 0..7
    const int lane = t & 63;
    const int g = lane >> 4;
    const int c = lane & 15;

    __shared__ __align__(16) char smem[76928];
    char* pb     = smem + 49152;             // P buffers (main loop)
    char* qsb    = smem + 49152;             // phase0 alias: q [128][64] swz
    char* lutkb  = smem + 8192;              // phase0 alias of ktb1
    USH* qrelb   = (USH*)(smem + 65536);     // [128][20] bf16
    USH* lvfb    = (USH*)(smem + 70656);     // [17][64] bf16
    USH* tapssb  = (USH*)(smem + 72832);     // [128][16] bf16 p values

    const USH* qp  = qb   + (size_t)bh * (S_LEN * DK);
    const USH* kp  = kbuf + (size_t)bh * (S_LEN * DK);
    const USH* vtp = vtg  + (size_t)bh * (S_LEN * DK);  // [d=64][s=1024]

    // async stage of one 64x64 K tile + V^T tile into buffer slot 'slot'
    auto stage = [&](int j0, int slot) {
        const int o = t * 16;
        const int row = o >> 7;
        const int chunk = (o >> 4) & 7;
        const int sc = (chunk ^ (row & 7)) * 8;
        gload16(kp + (size_t)(j0 + row) * DK + sc, smem + slot * 8192 + o);
        gload16(vtp + (size_t)row * S_LEN + j0 + sc, smem + 24576 + slot * 8192 + o);
    };

    // ---- phase 0: issue tile-0 loads; stage q (swz) + lut_k + lut_v ----
    stage(0, 0);
    for (int f = t; f < 2048; f += 512) {
        const int row = f >> 4, c4 = (f & 15) * 4;
        unsigned byte = ((unsigned)(row * 128 + c4 * 2)) ^ (((unsigned)row & 7) << 4);
        *(ushort4*)(qsb + byte) = *(const ushort4*)&qp[(size_t)(i0 + row) * DK + c4];
    }
    // lut_k -> bf16 LDS [32][64], rows 17..31 zero, swizzled (in ktb1)
    for (int e = t; e < 32 * 64; e += 512) {
        const int row = e >> 6, d = e & 63;
        const USH v = (row < 17) ? (USH)f2b(lut_k[row * 64 + d]) : (USH)0;
        unsigned byte = ((unsigned)(row * 128 + d * 2)) ^ (((unsigned)row & 7) << 4);
        *(USH*)(lutkb + byte) = v;
    }
    for (int e = t; e < 17 * 64; e += 512)
        lvfb[e] = (USH)f2b(lut_v[e]);
    __syncthreads();   // drains tile-0 gloads; qsb/lutkb/lvfb visible

    // Q fragments from swizzled bf16 LDS (wave w owns rows w*16..+15)
    bf16x8 qa[2];
    {
        const int row = w * 16 + c;
        #pragma unroll
        for (int kh = 0; kh < 2; ++kh) {
            unsigned byte = ((unsigned)(row * 128 + kh * 64 + g * 16))
                          ^ (((unsigned)row & 7) << 4);
            qa[kh] = *(const bf16x8*)(qsb + byte);
        }
    }

    // qrel via MFMA: lut_k rows as 17 virtual keys
    {
        f32x4 qr[2];
        qr[0] = (f32x4)0.f; qr[1] = (f32x4)0.f;
        #pragma unroll
        for (int sub2 = 0; sub2 < 2; ++sub2) {
            const int tap = sub2 * 16 + c;
            #pragma unroll
            for (int kh = 0; kh < 2; ++kh) {
                unsigned byte = ((unsigned)(tap * 128 + kh * 64 + g * 16))
                              ^ (((unsigned)tap & 7) << 4);
                bf16x8 lb = *(const bf16x8*)(lutkb + byte);
                qr[sub2] = __builtin_amdgcn_mfma_f32_16x16x32_bf16(
                    qa[kh], lb, qr[sub2], 0, 0, 0);
            }
        }
        #pragma unroll
        for (int sub2 = 0; sub2 < 2; ++sub2) {
            const int tap = sub2 * 16 + c;
            if (tap < 17) {
                #pragma unroll
                for (int r = 0; r < 4; ++r)
                    qrelb[(w * 16 + g * 4 + r) * 20 + tap] = (USH)f2b(qr[sub2][r]);
            }
        }
    }
    // hoist tap-0 qrel (own-wave rows; same-wave DS order, no barrier)
    float qrel0s[4];
    #pragma unroll
    for (int r = 0; r < 4; ++r)
        qrel0s[r] = b2f(qrelb[(w * 16 + g * 4 + r) * 20]) * EXPSCALE;

    __syncthreads();   // ALL qsb/lutkb reads done; ktb1/pb now writable

    const int NT = 2 * ib + 2;
    if (1 < NT) stage(64, 1);      // pre-loop: tile 1 in flight (always true)

    f32x4 acc[4];
    #pragma unroll
    for (int dt = 0; dt < 4; ++dt) acc[dt] = (f32x4)0.f;
    float l_r[4];   // per-lane PARTIAL row sums (reduced in epilogue)
    #pragma unroll
    for (int r = 0; r < 4; ++r) l_r[r] = 0.f;

    const int wrow0 = i0 + w * 16;   // first q-row owned by this wave
    int cur = 0;                     // tile t resides in slot (t % 3)
    for (int tile = 0; tile < NT; ++tile) {
        const int nxt2 = tile + 2;
        const int slot2 = (cur + 2 >= 3) ? cur - 1 : cur + 2;
        if (nxt2 < NT)
            stage(nxt2 << 6, slot2);

        // ---- per-wave fully-masked skip (wave-uniform condition) ----
        if (tile * 64 > wrow0 + 15) {
            if (nxt2 < NT) asm volatile("s_waitcnt vmcnt(2)" ::: "memory");
            else           asm volatile("s_waitcnt vmcnt(0)" ::: "memory");
            __builtin_amdgcn_s_barrier();
            cur = (cur + 1 == 3) ? 0 : cur + 1;
            continue;
        }

        const char* ktb = smem + cur * 8192;
        const char* vtb = smem + 24576 + cur * 8192;

        // ---- QK^T ----
        float p[4][4];
        __builtin_amdgcn_s_setprio(1);
        f32x4 s[4];
        #pragma unroll
        for (int sub = 0; sub < 4; ++sub) {
            s[sub] = (f32x4)0.f;
            const int krow = sub * 16 + c;
            #pragma unroll
            for (int kh = 0; kh < 2; ++kh) {
                unsigned byte = ((unsigned)krow << 7) + ((unsigned)kh << 6) + ((unsigned)g << 4);
                byte ^= (unsigned)(krow & 7) << 4;
                bf16x8 kb = *(const bf16x8*)(ktb + byte);
                s[sub] = __builtin_amdgcn_mfma_f32_16x16x32_bf16(qa[kh], kb, s[sub], 0, 0, 0);
            }
        }
        __builtin_amdgcn_s_setprio(0);

        if (tile * 64 + 79 <= wrow0) {
            // ---- per-wave interior: dj <= -16 -> tap index 0 everywhere ----
            #pragma unroll
            for (int sub = 0; sub < 4; ++sub)
                #pragma unroll
                for (int r = 0; r < 4; ++r)
                    p[sub][r] = fast_exp2(s[sub][r] * EXPSCALE + qrel0s[r]);
        } else {
            // ---- boundary: clamped tap lookup + causal mask + tap capture ----
            #pragma unroll
            for (int sub = 0; sub < 4; ++sub) {
                const int dbase = tile * 64 + (sub * 16 + c) - i0 - (w * 16 + g * 4);
                #pragma unroll
                for (int r = 0; r < 4; ++r) {
                    const int dj = dbase - r;
                    int t17 = dj + 16;
                    t17 = t17 < 0 ? 0 : (t17 > 16 ? 16 : t17);
                    const int il = w * 16 + g * 4 + r;
                    float pv = fast_exp2((s[sub][r] + b2f(qrelb[il * 20 + t17])) * EXPSCALE);
                    if (dj > 0) pv = 0.f;
                    p[sub][r] = pv;
                    if (dj >= -15 && dj <= 0)
                        tapssb[il * 16 + dj + 15] = (USH)f2b(pv);
                }
            }
        }

        // ---- accumulate per-lane partial row sums ----
        #pragma unroll
        for (int r = 0; r < 4; ++r)
            l_r[r] += (p[0][r] + p[1][r]) + (p[2][r] + p[3][r]);

        // ---- P -> per-wave LDS (bf16, [16][64], ^(row&7)<<4) ----
        char* pw = pb + w * 2048;
        #pragma unroll
        for (int sub = 0; sub < 4; ++sub)
            #pragma unroll
            for (int r = 0; r < 4; ++r) {
                const int row = g * 4 + r;
                unsigned byte = ((unsigned)row << 7) + (((unsigned)(sub * 16 + c)) << 1);
                byte ^= (unsigned)(row & 7) << 4;
                *(short*)(pw + byte) = f2b(p[sub][r]);
            }

        // ---- PV ----
        bf16x8 pa[2];
        #pragma unroll
        for (int jh = 0; jh < 2; ++jh) {
            unsigned byte = ((unsigned)c << 7) + ((unsigned)jh << 6) + ((unsigned)g << 4);
            byte ^= (unsigned)(c & 7) << 4;
            pa[jh] = *(const bf16x8*)(pw + byte);
        }
        __builtin_amdgcn_s_setprio(1);
        #pragma unroll
        for (int dt = 0; dt < 4; ++dt) {
            const int d = dt * 16 + c;
            #pragma unroll
            for (int jh = 0; jh < 2; ++jh) {
                unsigned byte = ((unsigned)d << 7) + ((unsigned)jh << 6) + ((unsigned)g << 4);
                byte ^= (unsigned)(d & 7) << 4;
                bf16x8 vb = *(const bf16x8*)(vtb + byte);
                acc[dt] = __builtin_amdgcn_mfma_f32_16x16x32_bf16(pa[jh], vb, acc[dt], 0, 0, 0);
            }
        }
        __builtin_amdgcn_s_setprio(0);

        // ---- counted-vmcnt barrier: keep t+2's loads in flight ----
        if (nxt2 < NT) asm volatile("s_waitcnt vmcnt(2)" ::: "memory");
        else           asm volatile("s_waitcnt vmcnt(0)" ::: "memory");
        __builtin_amdgcn_s_barrier();
        cur = (cur + 1 == 3) ? 0 : cur + 1;
    }

    // ---- epilogue: reduce row sums, taps + bin-0 residual, write ----
    const int rbase = w * 16 + g * 4;
    #pragma unroll
    for (int r = 0; r < 4; ++r) {
        float lsum = l_r[r];
        #pragma unroll
        for (int msk = 1; msk < 16; msk <<= 1)
            lsum += __shfl_xor(lsum, msk);
        const int il = rbase + r;
        float c0 = lsum;
        float tp[16];
        #pragma unroll
        for (int tap = 0; tap < 16; ++tap) {
            const int jg = i0 + il + tap - 15;
            const float pv = (jg >= 0) ? b2f(tapssb[il * 16 + tap]) : 0.f;
            tp[tap] = pv;
            c0 -= pv;
        }
        const float invl = 1.f / lsum;
        #pragma unroll
        for (int dt = 0; dt < 4; ++dt) {
            const int d = dt * 16 + c;
            float o = acc[dt][r] + c0 * b2f(lvfb[d]);
            #pragma unroll
            for (int tap = 0; tap < 16; ++tap)
                o += tp[tap] * b2f(lvfb[(tap + 1) * 64 + d]);
            o *= invl;
            ao[((size_t)b * S_LEN + (i0 + il)) * D_MODEL + h * DK + d] = (USH)f2b(o);
        }
    }
}

// ---------------------------------------------------------------------------
extern "C" void kernel_launch(void* const* d_in, const int* in_sizes, int n_in,
                              void* d_out, int out_size, void* d_ws, size_t ws_size,
                              hipStream_t stream) {
    const float* x      = (const float*)d_in[0];
    const float* W_attn = (const float*)d_in[1];
    const float* b_attn = (const float*)d_in[2];
    const float* W_proj = (const float*)d_in[3];
    const float* b_proj = (const float*)d_in[4];
    const float* lut_k  = (const float*)d_in[5];
    const float* lut_v  = (const float*)d_in[6];
    float* out = (float*)d_out;

    // workspace layout (all USH)
    USH* qb    = (USH*)d_ws;            // 8M
    USH* kb    = qb + HSZ;              // 8M
    USH* vb    = kb + HSZ;              // 8M (row-major V)
    USH* vtg   = vb + HSZ;              // 8M (per-head transposed V)
    USH* aob   = vtg + HSZ;             // 8M
    USH* xb    = aob + HSZ;             // 8M
    USH* watt  = xb + HSZ;              // 3M
    USH* wproj = watt + 3145728;        // 1M

    // 0) conversions
    conv_bf16_kernel<<<HSZ / (256 * 8), 256, 0, stream>>>(x, xb);
    transp_bf16_kernel<<<dim3(3072 / 64, 1024 / 64), 256, 0, stream>>>(
        W_attn, watt, 1024, 3072);
    transp_bf16_kernel<<<dim3(1024 / 64, 1024 / 64), 256, 0, stream>>>(
        W_proj, wproj, 1024, 1024);

    // 1) QKV projection (bf16 MFMA), coalesced row-major outputs
    mfma_gemm_kernel<1><<<dim3(3072 / 128, 8192 / 128), 256, 0, stream>>>(
        xb, watt, b_attn, nullptr, qb, kb, vb, 8192, 3072, 1024);

    // 1b) per-head V transpose (coalesced LDS-tile kernel, ~6 us)
    vtransp_kernel<<<2048, 256, 0, stream>>>(vb, vtg);

    // 2) attention (tri-buffered counted-vmcnt pipeline)
    attn_mfma_kernel<<<1024, 512, 0, stream>>>(qb, kb, vtg, lut_k, lut_v, aob);

    // 3) output projection (bf16 MFMA)
    mfma_gemm_kernel<0><<<dim3(1024 / 128, 8192 / 128), 256, 0, stream>>>(
        aob, wproj, b_proj, out, nullptr, nullptr, nullptr, 8192, 1024, 1024);
}

// Round 15
// 199.178 us; speedup vs baseline: 1.0587x; 1.0442x over previous
//
#include <hip/hip_runtime.h>
#include <hip/hip_bf16.h>
#include <math.h>

#define NH 16
#define S_LEN 1024
#define DK 64
#define D_MODEL 1024
#define HSZ 8388608          // B*NH*S*DK elements per q/k/v buffer

typedef __attribute__((ext_vector_type(8))) short bf16x8;
typedef __attribute__((ext_vector_type(4))) float f32x4;
typedef unsigned short USH;

#define EXPSCALE 0.1803368801111204f   // 0.125 * log2(e)

__device__ __forceinline__ float fast_exp2(float x) {
    return __builtin_amdgcn_exp2f(x);
}

__device__ __forceinline__ short f2b(float x) {
    union { __hip_bfloat16 h; short s; } u;
    u.h = __float2bfloat16(x);
    return u.s;
}
__device__ __forceinline__ float b2f(USH u) {
    union { unsigned i; float f; } x;
    x.i = (unsigned)u << 16;
    return x.f;
}

__device__ __forceinline__ void gload16(const void* src, void* lds) {
    __builtin_amdgcn_global_load_lds(
        (const __attribute__((address_space(1))) void*)src,
        (__attribute__((address_space(3))) void*)lds,
        16, 0, 0);
}

// ---------------------------------------------------------------------------
// Fused prep: fp32->bf16 conv of x  +  transpose-convert of W_attn, W_proj.
// blocks [0,4096): conv; [4096,4864): W_attn 64x64 tiles; [4864,5120): W_proj.
// ---------------------------------------------------------------------------
__global__ __launch_bounds__(256)
void prep_kernel(const float* __restrict__ x, USH* __restrict__ xb,
                 const float* __restrict__ W_attn, USH* __restrict__ watt,
                 const float* __restrict__ W_proj, USH* __restrict__ wproj) {
    const int blk = blockIdx.x;
    const int t = threadIdx.x;
    if (blk < 4096) {
        const int i = (blk * 256 + t) * 8;
        const float4 a = *(const float4*)&x[i];
        const float4 b = *(const float4*)&x[i + 4];
        ushort4 o0, o1;
        o0.x = (USH)f2b(a.x); o0.y = (USH)f2b(a.y); o0.z = (USH)f2b(a.z); o0.w = (USH)f2b(a.w);
        o1.x = (USH)f2b(b.x); o1.y = (USH)f2b(b.y); o1.z = (USH)f2b(b.z); o1.w = (USH)f2b(b.w);
        *(ushort4*)&xb[i] = o0;
        *(ushort4*)&xb[i + 4] = o1;
        return;
    }
    __shared__ USH Ts[64][65];
    const float* in;
    USH* out;
    int R, C, r0, c0;
    if (blk < 4864) {
        const int idx = blk - 4096;
        in = W_attn; out = watt; R = 1024; C = 3072;
        c0 = (idx % 48) * 64; r0 = (idx / 48) * 64;
    } else {
        const int idx = blk - 4864;
        in = W_proj; out = wproj; R = 1024; C = 1024;
        c0 = (idx % 16) * 64; r0 = (idx / 16) * 64;
    }
    const int tr = t >> 4;
    const int tc4 = (t & 15) * 4;
    #pragma unroll
    for (int ph = 0; ph < 4; ++ph) {
        const int r = ph * 16 + tr;
        const float4 v = *(const float4*)&in[(size_t)(r0 + r) * C + c0 + tc4];
        Ts[tc4 + 0][r] = (USH)f2b(v.x);
        Ts[tc4 + 1][r] = (USH)f2b(v.y);
        Ts[tc4 + 2][r] = (USH)f2b(v.z);
        Ts[tc4 + 3][r] = (USH)f2b(v.w);
    }
    __syncthreads();
    #pragma unroll
    for (int ph = 0; ph < 4; ++ph) {
        const int cc = ph * 16 + tr;
        ushort4 o;
        o.x = Ts[cc][tc4 + 0]; o.y = Ts[cc][tc4 + 1];
        o.z = Ts[cc][tc4 + 2]; o.w = Ts[cc][tc4 + 3];
        *(ushort4*)&out[(size_t)(c0 + cc) * R + r0 + tc4] = o;
    }
}

// ---------------------------------------------------------------------------
// Per-head V transpose (bf16): in [bh][s][64] -> out [bh][d=64][s=1024]
// ---------------------------------------------------------------------------
__global__ __launch_bounds__(256)
void vtransp_kernel(const USH* __restrict__ in, USH* __restrict__ out) {
    __shared__ USH T[64][72];
    const int bh = blockIdx.x >> 4;
    const int s0 = (blockIdx.x & 15) * 64;
    const int r = threadIdx.x >> 4;
    const int c4 = (threadIdx.x & 15) * 4;
    #pragma unroll
    for (int ph = 0; ph < 4; ++ph) {
        const int row = ph * 16 + r;   // s offset
        const ushort4 v = *(const ushort4*)
            &in[((size_t)bh * S_LEN + s0 + row) * DK + c4];
        T[row][c4 + 0] = v.x; T[row][c4 + 1] = v.y;
        T[row][c4 + 2] = v.z; T[row][c4 + 3] = v.w;
    }
    __syncthreads();
    #pragma unroll
    for (int ph = 0; ph < 4; ++ph) {
        const int d = ph * 16 + r;
        ushort4 o;
        o.x = T[c4 + 0][d]; o.y = T[c4 + 1][d];
        o.z = T[c4 + 2][d]; o.w = T[c4 + 3][d];
        *(ushort4*)&out[(size_t)bh * (S_LEN * DK) + (size_t)d * S_LEN + s0 + c4] = o;
    }
}

// ---------------------------------------------------------------------------
// QKV GEMM: 256x256 tile, BK=32, 512 threads (8 waves 2Mx4N), TRI-BUFFERED
// counted-vmcnt pipeline: vmcnt(4)+barrier at iter top (tile t+1's loads
// stay in flight across every barrier); stage(t+2) issued AFTER the barrier
// (barrier proves all waves finished slot(t-1) reads -> overwrite safe).
// 32 MFMA per barrier per wave (vs 8 in the m97 structure).
// M=8192 N=3072 K=1024; XCD-swizzled 384-block grid.
// LDS 96KB: 3 slots x (A[256][32] 16KB + B[256][32] 16KB).
// Swizzle: LDS(row, chunk) = src(row, chunk^(row&3)); read chunk=g^(row&3).
// ---------------------------------------------------------------------------
__global__ __launch_bounds__(512)
void qkv_gemm_kernel(const USH* __restrict__ A, const USH* __restrict__ Bt,
                     const float* __restrict__ bias,
                     USH* __restrict__ Cq, USH* __restrict__ Ck,
                     USH* __restrict__ Cv) {
    __shared__ __align__(16) USH lds[3 * 16384];   // 96 KB
    const int t = threadIdx.x;
    const int w = t >> 6, lane = t & 63, g = lane >> 4, c = lane & 15;
    const int wm = w >> 2, wn = w & 3;             // 2 x 4 waves
    const int bid = blockIdx.x;
    const int swz = (bid & 7) * 48 + (bid >> 3);   // 384 % 8 == 0: bijective
    const int bn0 = (swz % 12) * 256;
    const int bm0 = (swz / 12) * 256;

    // stage K-tile kt into slot: A half + B half, 4 gload16/thread
    auto stage = [&](int kt, int slot) {
        const int k0 = kt * 32;
        USH* base = lds + slot * 16384;
        #pragma unroll
        for (int q = 0; q < 2; ++q) {
            const int o = t * 16 + q * 8192;       // byte offset in 16KB region
            const int row = o >> 6;
            const int chunk = (o >> 4) & 3;
            const int sc = (chunk ^ (row & 3)) * 8;
            gload16(A + (size_t)(bm0 + row) * 1024 + k0 + sc, (char*)base + o);
            gload16(Bt + (size_t)(bn0 + row) * 1024 + k0 + sc,
                    (char*)(base + 8192) + o);
        }
    };

    // fragment read byte offsets (relative to slot base, 32KB region)
    unsigned aoff[8], boff[4];
    #pragma unroll
    for (int i = 0; i < 8; ++i) {
        const int row = wm * 128 + i * 16 + c;
        aoff[i] = (unsigned)(row * 64) + (((unsigned)(g ^ (row & 3))) << 4);
    }
    #pragma unroll
    for (int j = 0; j < 4; ++j) {
        const int row = wn * 64 + j * 16 + c;
        boff[j] = 16384u + (unsigned)(row * 64) + (((unsigned)(g ^ (row & 3))) << 4);
    }

    f32x4 acc[8][4];
    #pragma unroll
    for (int i = 0; i < 8; ++i)
        #pragma unroll
        for (int j = 0; j < 4; ++j) acc[i][j] = (f32x4)0.f;

    stage(0, 0);
    stage(1, 1);

    int cur = 0;
    for (int kt = 0; kt < 32; ++kt) {
        // tile kt's own loads done (leave kt+1's 4 in flight), then barrier:
        // all waves' tile-kt loads landed AND all waves done reading slot(kt-1).
        if (kt < 31) asm volatile("s_waitcnt vmcnt(4)" ::: "memory");
        else         asm volatile("s_waitcnt vmcnt(0)" ::: "memory");
        __builtin_amdgcn_s_barrier();

        const int slot2 = (cur + 2 >= 3) ? cur - 1 : cur + 2;  // == (kt-1)%3
        if (kt + 2 < 32)
            stage(kt + 2, slot2);

        const char* sb = (const char*)lds + cur * 32768;
        bf16x8 af[8], bfr[4];
        #pragma unroll
        for (int i = 0; i < 8; ++i) af[i] = *(const bf16x8*)(sb + aoff[i]);
        #pragma unroll
        for (int j = 0; j < 4; ++j) bfr[j] = *(const bf16x8*)(sb + boff[j]);

        __builtin_amdgcn_s_setprio(1);
        #pragma unroll
        for (int i = 0; i < 8; ++i)
            #pragma unroll
            for (int j = 0; j < 4; ++j)
                acc[i][j] = __builtin_amdgcn_mfma_f32_16x16x32_bf16(
                    af[i], bfr[j], acc[i][j], 0, 0, 0);
        __builtin_amdgcn_s_setprio(0);

        cur = (cur + 1 == 3) ? 0 : cur + 1;
    }

    // epilogue: bias + scatter q/k/v (bf16, row-major coalesced layouts)
    #pragma unroll
    for (int i = 0; i < 8; ++i) {
        #pragma unroll
        for (int reg = 0; reg < 4; ++reg) {
            const int m = bm0 + wm * 128 + i * 16 + g * 4 + reg;
            const int b = m >> 10, s = m & 1023;
            #pragma unroll
            for (int j = 0; j < 4; ++j) {
                const int n = bn0 + wn * 64 + j * 16 + c;
                const float v = acc[i][j][reg] + bias[n];
                const int which = n >> 10;
                const int h = (n & 1023) >> 6, d = n & 63;
                const size_t idx = (((size_t)(b * NH + h)) * S_LEN + s) * DK + d;
                if (which == 0)      Cq[idx] = (USH)f2b(v);
                else if (which == 1) Ck[idx] = (USH)f2b(v);
                else                 Cv[idx] = (USH)f2b(v);
            }
        }
    }
}

// ---------------------------------------------------------------------------
// bf16 MFMA GEMM (m97 structure) — used for the output projection.
// ---------------------------------------------------------------------------
__global__ __launch_bounds__(256)
void proj_gemm_kernel(const USH* __restrict__ A, const USH* __restrict__ Bt,
                      const float* __restrict__ bias, float* __restrict__ Cf,
                      int M, int N, int K) {
    __shared__ __align__(16) USH As[128 * 32];
    __shared__ __align__(16) USH Bs[128 * 32];
    const int t = threadIdx.x;
    const int w = t >> 6, lane = t & 63, g = lane >> 4, c = lane & 15;
    const int wm = w >> 1, wn = w & 1;
    const int bm0 = blockIdx.y * 128, bn0 = blockIdx.x * 128;

    const int sk = ((t & 3) ^ ((t >> 3) & 3)) * 8;
    const USH* pa0 = A + (size_t)(bm0 + (t >> 2)) * K + sk;
    const USH* pa1 = pa0 + (size_t)64 * K;
    const USH* pb0 = Bt + (size_t)(bn0 + (t >> 2)) * K + sk;
    const USH* pb1 = pb0 + (size_t)64 * K;
    USH* ldsA0 = &As[(t & ~63) * 8];
    USH* ldsA1 = ldsA0 + 2048;
    USH* ldsB0 = &Bs[(t & ~63) * 8];
    USH* ldsB1 = ldsB0 + 2048;

    unsigned aoff[4], boff[4];
    #pragma unroll
    for (int i = 0; i < 4; ++i) {
        const int r = wm * 64 + i * 16 + c;
        aoff[i] = ((unsigned)(r * 64 + g * 16)) ^ ((((unsigned)r >> 1) & 3) << 4);
        const int n = wn * 64 + i * 16 + c;
        boff[i] = ((unsigned)(n * 64 + g * 16)) ^ ((((unsigned)n >> 1) & 3) << 4);
    }

    f32x4 acc[4][4];
    #pragma unroll
    for (int i = 0; i < 4; ++i)
        #pragma unroll
        for (int j = 0; j < 4; ++j) acc[i][j] = (f32x4)0.f;

    for (int k0 = 0; k0 < K; k0 += 32) {
        gload16(pa0 + k0, ldsA0);
        gload16(pa1 + k0, ldsA1);
        gload16(pb0 + k0, ldsB0);
        gload16(pb1 + k0, ldsB1);
        __syncthreads();

        bf16x8 af[4], bfr[4];
        #pragma unroll
        for (int i = 0; i < 4; ++i) af[i] = *(const bf16x8*)((const char*)As + aoff[i]);
        #pragma unroll
        for (int j = 0; j < 4; ++j) bfr[j] = *(const bf16x8*)((const char*)Bs + boff[j]);
        #pragma unroll
        for (int i = 0; i < 4; ++i)
            #pragma unroll
            for (int j = 0; j < 4; ++j)
                acc[i][j] = __builtin_amdgcn_mfma_f32_16x16x32_bf16(
                    af[i], bfr[j], acc[i][j], 0, 0, 0);
        __syncthreads();
    }

    #pragma unroll
    for (int i = 0; i < 4; ++i) {
        #pragma unroll
        for (int reg = 0; reg < 4; ++reg) {
            const int m = bm0 + wm * 64 + i * 16 + g * 4 + reg;
            #pragma unroll
            for (int j = 0; j < 4; ++j) {
                const int n = bn0 + wn * 64 + j * 16 + c;
                Cf[(size_t)m * N + n] = acc[i][j][reg] + bias[n];
            }
        }
    }
}

// ---------------------------------------------------------------------------
// MFMA flash attention (R14 structure, unchanged): 8 waves x 128 q-rows,
// tri-buffered counted-vmcnt staging, fixed-shift softmax.
// ---------------------------------------------------------------------------
__global__ __launch_bounds__(512, 4)
void attn_mfma_kernel(const USH* __restrict__ qb,
                      const USH* __restrict__ kbuf,
                      const USH* __restrict__ vtg,
                      const float* __restrict__ lut_k,
                      const float* __restrict__ lut_v,
                      USH* __restrict__ ao) {
    const int bid = blockIdx.x;
    const int logical = (bid & 7) * 128 + (bid >> 3);   // XCD-contiguous bh
    const int ib = 7 - (logical & 7);                   // LPT: big ib first
    const int bh = logical >> 3;
    const int b = bh >> 4, h = bh & 15;
    const int i0 = ib * 128;
    const int t = threadIdx.x;
    const int w = t >> 6;          // 0..7
    const int lane = t & 63;
    const int g = lane >> 4;
    const int c = lane & 15;

    __shared__ __align__(16) char smem[76928];
    char* pb     = smem + 49152;             // P buffers (main loop)
    char* qsb    = smem + 49152;             // phase0 alias: q [128][64] swz
    char* lutkb  = smem + 8192;              // phase0 alias of ktb1
    USH* qrelb   = (USH*)(smem + 65536);     // [128][20] bf16
    USH* lvfb    = (USH*)(smem + 70656);     // [17][64] bf16
    USH* tapssb  = (USH*)(smem + 72832);     // [128][16] bf16 p values

    const USH* qp  = qb   + (size_t)bh * (S_LEN * DK);
    const USH* kp  = kbuf + (size_t)bh * (S_LEN * DK);
    const USH* vtp = vtg  + (size_t)bh * (S_LEN * DK);  // [d=64][s=1024]

    auto stage = [&](int j0, int slot) {
        const int o = t * 16;
        const int row = o >> 7;
        const int chunk = (o >> 4) & 7;
        const int sc = (chunk ^ (row & 7)) * 8;
        gload16(kp + (size_t)(j0 + row) * DK + sc, smem + slot * 8192 + o);
        gload16(vtp + (size_t)row * S_LEN + j0 + sc, smem + 24576 + slot * 8192 + o);
    };

    // ---- phase 0 ----
    stage(0, 0);
    for (int f = t; f < 2048; f += 512) {
        const int row = f >> 4, c4 = (f & 15) * 4;
        unsigned byte = ((unsigned)(row * 128 + c4 * 2)) ^ (((unsigned)row & 7) << 4);
        *(ushort4*)(qsb + byte) = *(const ushort4*)&qp[(size_t)(i0 + row) * DK + c4];
    }
    for (int e = t; e < 32 * 64; e += 512) {
        const int row = e >> 6, d = e & 63;
        const USH v = (row < 17) ? (USH)f2b(lut_k[row * 64 + d]) : (USH)0;
        unsigned byte = ((unsigned)(row * 128 + d * 2)) ^ (((unsigned)row & 7) << 4);
        *(USH*)(lutkb + byte) = v;
    }
    for (int e = t; e < 17 * 64; e += 512)
        lvfb[e] = (USH)f2b(lut_v[e]);
    __syncthreads();

    bf16x8 qa[2];
    {
        const int row = w * 16 + c;
        #pragma unroll
        for (int kh = 0; kh < 2; ++kh) {
            unsigned byte = ((unsigned)(row * 128 + kh * 64 + g * 16))
                          ^ (((unsigned)row & 7) << 4);
            qa[kh] = *(const bf16x8*)(qsb + byte);
        }
    }

    {
        f32x4 qr[2];
        qr[0] = (f32x4)0.f; qr[1] = (f32x4)0.f;
        #pragma unroll
        for (int sub2 = 0; sub2 < 2; ++sub2) {
            const int tap = sub2 * 16 + c;
            #pragma unroll
            for (int kh = 0; kh < 2; ++kh) {
                unsigned byte = ((unsigned)(tap * 128 + kh * 64 + g * 16))
                              ^ (((unsigned)tap & 7) << 4);
                bf16x8 lb = *(const bf16x8*)(lutkb + byte);
                qr[sub2] = __builtin_amdgcn_mfma_f32_16x16x32_bf16(
                    qa[kh], lb, qr[sub2], 0, 0, 0);
            }
        }
        #pragma unroll
        for (int sub2 = 0; sub2 < 2; ++sub2) {
            const int tap = sub2 * 16 + c;
            if (tap < 17) {
                #pragma unroll
                for (int r = 0; r < 4; ++r)
                    qrelb[(w * 16 + g * 4 + r) * 20 + tap] = (USH)f2b(qr[sub2][r]);
            }
        }
    }
    float qrel0s[4];
    #pragma unroll
    for (int r = 0; r < 4; ++r)
        qrel0s[r] = b2f(qrelb[(w * 16 + g * 4 + r) * 20]) * EXPSCALE;

    __syncthreads();

    const int NT = 2 * ib + 2;
    if (1 < NT) stage(64, 1);

    f32x4 acc[4];
    #pragma unroll
    for (int dt = 0; dt < 4; ++dt) acc[dt] = (f32x4)0.f;
    float l_r[4];
    #pragma unroll
    for (int r = 0; r < 4; ++r) l_r[r] = 0.f;

    const int wrow0 = i0 + w * 16;
    int cur = 0;
    for (int tile = 0; tile < NT; ++tile) {
        const int nxt2 = tile + 2;
        const int slot2 = (cur + 2 >= 3) ? cur - 1 : cur + 2;
        if (nxt2 < NT)
            stage(nxt2 << 6, slot2);

        if (tile * 64 > wrow0 + 15) {
            if (nxt2 < NT) asm volatile("s_waitcnt vmcnt(2)" ::: "memory");
            else           asm volatile("s_waitcnt vmcnt(0)" ::: "memory");
            __builtin_amdgcn_s_barrier();
            cur = (cur + 1 == 3) ? 0 : cur + 1;
            continue;
        }

        const char* ktb = smem + cur * 8192;
        const char* vtb = smem + 24576 + cur * 8192;

        float p[4][4];
        __builtin_amdgcn_s_setprio(1);
        f32x4 s[4];
        #pragma unroll
        for (int sub = 0; sub < 4; ++sub) {
            s[sub] = (f32x4)0.f;
            const int krow = sub * 16 + c;
            #pragma unroll
            for (int kh = 0; kh < 2; ++kh) {
                unsigned byte = ((unsigned)krow << 7) + ((unsigned)kh << 6) + ((unsigned)g << 4);
                byte ^= (unsigned)(krow & 7) << 4;
                bf16x8 kb = *(const bf16x8*)(ktb + byte);
                s[sub] = __builtin_amdgcn_mfma_f32_16x16x32_bf16(qa[kh], kb, s[sub], 0, 0, 0);
            }
        }
        __builtin_amdgcn_s_setprio(0);

        if (tile * 64 + 79 <= wrow0) {
            #pragma unroll
            for (int sub = 0; sub < 4; ++sub)
                #pragma unroll
                for (int r = 0; r < 4; ++r)
                    p[sub][r] = fast_exp2(s[sub][r] * EXPSCALE + qrel0s[r]);
        } else {
            #pragma unroll
            for (int sub = 0; sub < 4; ++sub) {
                const int dbase = tile * 64 + (sub * 16 + c) - i0 - (w * 16 + g * 4);
                #pragma unroll
                for (int r = 0; r < 4; ++r) {
                    const int dj = dbase - r;
                    int t17 = dj + 16;
                    t17 = t17 < 0 ? 0 : (t17 > 16 ? 16 : t17);
                    const int il = w * 16 + g * 4 + r;
                    float pv = fast_exp2((s[sub][r] + b2f(qrelb[il * 20 + t17])) * EXPSCALE);
                    if (dj > 0) pv = 0.f;
                    p[sub][r] = pv;
                    if (dj >= -15 && dj <= 0)
                        tapssb[il * 16 + dj + 15] = (USH)f2b(pv);
                }
            }
        }

        #pragma unroll
        for (int r = 0; r < 4; ++r)
            l_r[r] += (p[0][r] + p[1][r]) + (p[2][r] + p[3][r]);

        char* pw = pb + w * 2048;
        #pragma unroll
        for (int sub = 0; sub < 4; ++sub)
            #pragma unroll
            for (int r = 0; r < 4; ++r) {
                const int row = g * 4 + r;
                unsigned byte = ((unsigned)row << 7) + (((unsigned)(sub * 16 + c)) << 1);
                byte ^= (unsigned)(row & 7) << 4;
                *(short*)(pw + byte) = f2b(p[sub][r]);
            }

        bf16x8 pa[2];
        #pragma unroll
        for (int jh = 0; jh < 2; ++jh) {
            unsigned byte = ((unsigned)c << 7) + ((unsigned)jh << 6) + ((unsigned)g << 4);
            byte ^= (unsigned)(c & 7) << 4;
            pa[jh] = *(const bf16x8*)(pw + byte);
        }
        __builtin_amdgcn_s_setprio(1);
        #pragma unroll
        for (int dt = 0; dt < 4; ++dt) {
            const int d = dt * 16 + c;
            #pragma unroll
            for (int jh = 0; jh < 2; ++jh) {
                unsigned byte = ((unsigned)d << 7) + ((unsigned)jh << 6) + ((unsigned)g << 4);
                byte ^= (unsigned)(d & 7) << 4;
                bf16x8 vb = *(const bf16x8*)(vtb + byte);
                acc[dt] = __builtin_amdgcn_mfma_f32_16x16x32_bf16(pa[jh], vb, acc[dt], 0, 0, 0);
            }
        }
        __builtin_amdgcn_s_setprio(0);

        if (nxt2 < NT) asm volatile("s_waitcnt vmcnt(2)" ::: "memory");
        else           asm volatile("s_waitcnt vmcnt(0)" ::: "memory");
        __builtin_amdgcn_s_barrier();
        cur = (cur + 1 == 3) ? 0 : cur + 1;
    }

    const int rbase = w * 16 + g * 4;
    #pragma unroll
    for (int r = 0; r < 4; ++r) {
        float lsum = l_r[r];
        #pragma unroll
        for (int msk = 1; msk < 16; msk <<= 1)
            lsum += __shfl_xor(lsum, msk);
        const int il = rbase + r;
        float c0 = lsum;
        float tp[16];
        #pragma unroll
        for (int tap = 0; tap < 16; ++tap) {
            const int jg = i0 + il + tap - 15;
            const float pv = (jg >= 0) ? b2f(tapssb[il * 16 + tap]) : 0.f;
            tp[tap] = pv;
            c0 -= pv;
        }
        const float invl = 1.f / lsum;
        #pragma unroll
        for (int dt = 0; dt < 4; ++dt) {
            const int d = dt * 16 + c;
            float o = acc[dt][r] + c0 * b2f(lvfb[d]);
            #pragma unroll
            for (int tap = 0; tap < 16; ++tap)
                o += tp[tap] * b2f(lvfb[(tap + 1) * 64 + d]);
            o *= invl;
            ao[((size_t)b * S_LEN + (i0 + il)) * D_MODEL + h * DK + d] = (USH)f2b(o);
        }
    }
}

// ---------------------------------------------------------------------------
extern "C" void kernel_launch(void* const* d_in, const int* in_sizes, int n_in,
                              void* d_out, int out_size, void* d_ws, size_t ws_size,
                              hipStream_t stream) {
    const float* x      = (const float*)d_in[0];
    const float* W_attn = (const float*)d_in[1];
    const float* b_attn = (const float*)d_in[2];
    const float* W_proj = (const float*)d_in[3];
    const float* b_proj = (const float*)d_in[4];
    const float* lut_k  = (const float*)d_in[5];
    const float* lut_v  = (const float*)d_in[6];
    float* out = (float*)d_out;

    // workspace layout (all USH)
    USH* qb    = (USH*)d_ws;            // 8M
    USH* kb    = qb + HSZ;              // 8M
    USH* vb    = kb + HSZ;              // 8M (row-major V)
    USH* vtg   = vb + HSZ;              // 8M (per-head transposed V)
    USH* aob   = vtg + HSZ;             // 8M
    USH* xb    = aob + HSZ;             // 8M
    USH* watt  = xb + HSZ;              // 3M
    USH* wproj = watt + 3145728;        // 1M

    // 0) fused prep: x->bf16, W_attn^T, W_proj^T
    prep_kernel<<<5120, 256, 0, stream>>>(x, xb, W_attn, watt, W_proj, wproj);

    // 1) QKV projection (256^2 tri-buffered counted-vmcnt)
    qkv_gemm_kernel<<<384, 512, 0, stream>>>(xb, watt, b_attn, qb, kb, vb);

    // 1b) per-head V transpose
    vtransp_kernel<<<2048, 256, 0, stream>>>(vb, vtg);

    // 2) attention
    attn_mfma_kernel<<<1024, 512, 0, stream>>>(qb, kb, vtg, lut_k, lut_v, aob);

    // 3) output projection (m97 structure)
    proj_gemm_kernel<<<dim3(1024 / 128, 8192 / 128), 256, 0, stream>>>(
        aob, wproj, b_proj, out, 8192, 1024, 1024);
}

// Round 16
// 178.958 us; speedup vs baseline: 1.1784x; 1.1130x over previous
//
#include <hip/hip_runtime.h>
#include <hip/hip_bf16.h>
#include <math.h>

#define NH 16
#define S_LEN 1024
#define DK 64
#define D_MODEL 1024
#define HSZ 8388608          // B*NH*S*DK elements per q/k/v buffer

typedef __attribute__((ext_vector_type(8))) short bf16x8;
typedef __attribute__((ext_vector_type(4))) float f32x4;
typedef unsigned short USH;

#define EXPSCALE 0.1803368801111204f   // 0.125 * log2(e)

__device__ __forceinline__ float fast_exp2(float x) {
    return __builtin_amdgcn_exp2f(x);
}

__device__ __forceinline__ short f2b(float x) {
    union { __hip_bfloat16 h; short s; } u;
    u.h = __float2bfloat16(x);
    return u.s;
}
__device__ __forceinline__ float b2f(USH u) {
    union { unsigned i; float f; } x;
    x.i = (unsigned)u << 16;
    return x.f;
}

__device__ __forceinline__ void gload16(const void* src, void* lds) {
    __builtin_amdgcn_global_load_lds(
        (const __attribute__((address_space(1))) void*)src,
        (__attribute__((address_space(3))) void*)lds,
        16, 0, 0);
}

// ---------------------------------------------------------------------------
// Fused prep: fp32->bf16 conv of x  +  transpose-convert of W_attn, W_proj.
// ---------------------------------------------------------------------------
__global__ __launch_bounds__(256)
void prep_kernel(const float* __restrict__ x, USH* __restrict__ xb,
                 const float* __restrict__ W_attn, USH* __restrict__ watt,
                 const float* __restrict__ W_proj, USH* __restrict__ wproj) {
    const int blk = blockIdx.x;
    const int t = threadIdx.x;
    if (blk < 4096) {
        const int i = (blk * 256 + t) * 8;
        const float4 a = *(const float4*)&x[i];
        const float4 b = *(const float4*)&x[i + 4];
        ushort4 o0, o1;
        o0.x = (USH)f2b(a.x); o0.y = (USH)f2b(a.y); o0.z = (USH)f2b(a.z); o0.w = (USH)f2b(a.w);
        o1.x = (USH)f2b(b.x); o1.y = (USH)f2b(b.y); o1.z = (USH)f2b(b.z); o1.w = (USH)f2b(b.w);
        *(ushort4*)&xb[i] = o0;
        *(ushort4*)&xb[i + 4] = o1;
        return;
    }
    __shared__ USH Ts[64][65];
    const float* in;
    USH* out;
    int R, C, r0, c0;
    if (blk < 4864) {
        const int idx = blk - 4096;
        in = W_attn; out = watt; R = 1024; C = 3072;
        c0 = (idx % 48) * 64; r0 = (idx / 48) * 64;
    } else {
        const int idx = blk - 4864;
        in = W_proj; out = wproj; R = 1024; C = 1024;
        c0 = (idx % 16) * 64; r0 = (idx / 16) * 64;
    }
    const int tr = t >> 4;
    const int tc4 = (t & 15) * 4;
    #pragma unroll
    for (int ph = 0; ph < 4; ++ph) {
        const int r = ph * 16 + tr;
        const float4 v = *(const float4*)&in[(size_t)(r0 + r) * C + c0 + tc4];
        Ts[tc4 + 0][r] = (USH)f2b(v.x);
        Ts[tc4 + 1][r] = (USH)f2b(v.y);
        Ts[tc4 + 2][r] = (USH)f2b(v.z);
        Ts[tc4 + 3][r] = (USH)f2b(v.w);
    }
    __syncthreads();
    #pragma unroll
    for (int ph = 0; ph < 4; ++ph) {
        const int cc = ph * 16 + tr;
        ushort4 o;
        o.x = Ts[cc][tc4 + 0]; o.y = Ts[cc][tc4 + 1];
        o.z = Ts[cc][tc4 + 2]; o.w = Ts[cc][tc4 + 3];
        *(ushort4*)&out[(size_t)(c0 + cc) * R + r0 + tc4] = o;
    }
}

// ---------------------------------------------------------------------------
// 256x128-tile GEMM, BK=32, 512 thr (8 waves 4Mx2N, 64x64 each), tri-buffered
// counted-vmcnt pipeline (3 gloads/stage -> vmcnt(3)). LDS 72KB -> 2 blk/CU.
// QKV=1: M=8192,N=3072,K=1024, grid 768. n-tiles with bn0>=2048 (V) write
//   vtg[bh][d][s] via in-LDS transpose (64KB, coalesced 16B stores).
// QKV=0: proj, fp32 row-major out + bias, N=1024, grid 256.
// Swizzle: LDS(row,chunk)=src(row,chunk^(row&3)); read chunk=g^(row&3).
// ---------------------------------------------------------------------------
template<int QKV>
__global__ __launch_bounds__(512)
void gemm256_kernel(const USH* __restrict__ A, const USH* __restrict__ Bt,
                    const float* __restrict__ bias,
                    float* __restrict__ Cf, USH* __restrict__ Cq,
                    USH* __restrict__ Ck, USH* __restrict__ Cvt,
                    int N, int NTILN) {
    __shared__ __align__(16) USH lds[36864];   // 72 KB
    const int t = threadIdx.x;
    const int w = t >> 6, lane = t & 63, g = lane >> 4, c = lane & 15;
    const int wm = w >> 1, wn = w & 1;         // 4M x 2N waves
    const int nwg = NTILN * 32;
    const int bid = blockIdx.x;
    const int swz = (bid & 7) * (nwg >> 3) + (bid >> 3);   // nwg%8==0 bijective
    const int bn0 = (swz % NTILN) * 128;
    const int bm0 = (swz / NTILN) * 256;

    // stage K-tile kt into slot: A 2 chunks + B 1 chunk per thread
    auto stage = [&](int kt, int slot) {
        const int k0 = kt * 32;
        char* base = (char*)lds + slot * 24576;
        #pragma unroll
        for (int q = 0; q < 2; ++q) {
            const int o = t * 16 + q * 8192;
            const int row = o >> 6;
            const int sc = (((o >> 4) & 3) ^ (row & 3)) * 8;
            gload16(A + (size_t)(bm0 + row) * 1024 + k0 + sc, base + o);
        }
        const int o = t * 16;
        const int row = o >> 6;
        const int sc = (((o >> 4) & 3) ^ (row & 3)) * 8;
        gload16(Bt + (size_t)(bn0 + row) * 1024 + k0 + sc, base + 16384 + o);
    };

    unsigned aoff[4], boff[4];
    #pragma unroll
    for (int i = 0; i < 4; ++i) {
        const int row = wm * 64 + i * 16 + c;
        aoff[i] = (unsigned)(row * 64) + (((unsigned)(g ^ (row & 3))) << 4);
        const int rn = wn * 64 + i * 16 + c;
        boff[i] = 16384u + (unsigned)(rn * 64) + (((unsigned)(g ^ (rn & 3))) << 4);
    }

    f32x4 acc[4][4];
    #pragma unroll
    for (int i = 0; i < 4; ++i)
        #pragma unroll
        for (int j = 0; j < 4; ++j) acc[i][j] = (f32x4)0.f;

    stage(0, 0);
    stage(1, 1);

    int cur = 0;
    for (int kt = 0; kt < 32; ++kt) {
        if (kt < 31) asm volatile("s_waitcnt vmcnt(3)" ::: "memory");
        else         asm volatile("s_waitcnt vmcnt(0)" ::: "memory");
        __builtin_amdgcn_s_barrier();

        const int slot2 = (cur + 2 >= 3) ? cur - 1 : cur + 2;
        if (kt + 2 < 32)
            stage(kt + 2, slot2);

        const char* sb = (const char*)lds + cur * 24576;
        bf16x8 af[4], bfr[4];
        #pragma unroll
        for (int i = 0; i < 4; ++i) af[i] = *(const bf16x8*)(sb + aoff[i]);
        #pragma unroll
        for (int j = 0; j < 4; ++j) bfr[j] = *(const bf16x8*)(sb + boff[j]);

        __builtin_amdgcn_s_setprio(1);
        #pragma unroll
        for (int i = 0; i < 4; ++i)
            #pragma unroll
            for (int j = 0; j < 4; ++j)
                acc[i][j] = __builtin_amdgcn_mfma_f32_16x16x32_bf16(
                    af[i], bfr[j], acc[i][j], 0, 0, 0);
        __builtin_amdgcn_s_setprio(0);

        cur = (cur + 1 == 3) ? 0 : cur + 1;
    }

    if (QKV) {
        if (bn0 < 2048) {
            // q / k: row-major coalesced scatter (which is tile-uniform)
            #pragma unroll
            for (int i = 0; i < 4; ++i) {
                #pragma unroll
                for (int reg = 0; reg < 4; ++reg) {
                    const int m = bm0 + wm * 64 + i * 16 + g * 4 + reg;
                    const int b = m >> 10, s = m & 1023;
                    #pragma unroll
                    for (int j = 0; j < 4; ++j) {
                        const int n = bn0 + wn * 64 + j * 16 + c;
                        const float v = acc[i][j][reg] + bias[n];
                        const int which = n >> 10;
                        const int h = (n & 1023) >> 6, d = n & 63;
                        const size_t idx = (((size_t)(b * NH + h)) * S_LEN + s) * DK + d;
                        if (which == 0) Cq[idx] = (USH)f2b(v);
                        else            Ck[idx] = (USH)f2b(v);
                    }
                }
            }
        } else {
            // V: in-LDS transpose -> vtg[bh][d][s], coalesced 16B stores.
            __syncthreads();   // all main-loop LDS reads complete
            #pragma unroll
            for (int i = 0; i < 4; ++i) {
                const int m_local = wm * 64 + i * 16 + g * 4;
                #pragma unroll
                for (int j = 0; j < 4; ++j) {
                    const int n_local = wn * 64 + j * 16 + c;
                    const int n = bn0 + n_local;
                    ushort4 pk;
                    pk.x = (USH)f2b(acc[i][j][0] + bias[n]);
                    pk.y = (USH)f2b(acc[i][j][1] + bias[n]);
                    pk.z = (USH)f2b(acc[i][j][2] + bias[n]);
                    pk.w = (USH)f2b(acc[i][j][3] + bias[n]);
                    unsigned byte = ((unsigned)(n_local * 512 + m_local * 2))
                                  ^ (((unsigned)n_local & 7) << 4);
                    *(ushort4*)((char*)lds + byte) = pk;
                }
            }
            __syncthreads();
            const int b = bm0 >> 10, s0 = bm0 & 1023;
            const int h0 = (bn0 & 1023) >> 6;
            #pragma unroll
            for (int e = 0; e < 8; ++e) {
                const int task = e * 512 + t;
                const int n_local = task >> 5;
                const int chunk = task & 31;
                unsigned byte = ((unsigned)(n_local * 512 + chunk * 16))
                              ^ (((unsigned)n_local & 7) << 4);
                bf16x8 v = *(const bf16x8*)((char*)lds + byte);
                const int h = h0 + (n_local >> 6);
                const int d = n_local & 63;
                *(bf16x8*)&Cvt[(((size_t)(b * NH + h)) * DK + d) * S_LEN
                               + s0 + chunk * 8] = v;
            }
        }
    } else {
        #pragma unroll
        for (int i = 0; i < 4; ++i) {
            #pragma unroll
            for (int reg = 0; reg < 4; ++reg) {
                const int m = bm0 + wm * 64 + i * 16 + g * 4 + reg;
                #pragma unroll
                for (int j = 0; j < 4; ++j) {
                    const int n = bn0 + wn * 64 + j * 16 + c;
                    Cf[(size_t)m * N + n] = acc[i][j][reg] + bias[n];
                }
            }
        }
    }
}

// ---------------------------------------------------------------------------
// MFMA flash attention (R14/R15 structure, unchanged): 8 waves x 128 q-rows,
// tri-buffered counted-vmcnt staging, fixed-shift softmax.
// ---------------------------------------------------------------------------
__global__ __launch_bounds__(512, 4)
void attn_mfma_kernel(const USH* __restrict__ qb,
                      const USH* __restrict__ kbuf,
                      const USH* __restrict__ vtg,
                      const float* __restrict__ lut_k,
                      const float* __restrict__ lut_v,
                      USH* __restrict__ ao) {
    const int bid = blockIdx.x;
    const int logical = (bid & 7) * 128 + (bid >> 3);   // XCD-contiguous bh
    const int ib = 7 - (logical & 7);                   // LPT: big ib first
    const int bh = logical >> 3;
    const int b = bh >> 4, h = bh & 15;
    const int i0 = ib * 128;
    const int t = threadIdx.x;
    const int w = t >> 6;          // 0..7
    const int lane = t & 63;
    const int g = lane >> 4;
    const int c = lane & 15;

    __shared__ __align__(16) char smem[76928];
    char* pb     = smem + 49152;             // P buffers (main loop)
    char* qsb    = smem + 49152;             // phase0 alias: q [128][64] swz
    char* lutkb  = smem + 8192;              // phase0 alias of ktb1
    USH* qrelb   = (USH*)(smem + 65536);     // [128][20] bf16
    USH* lvfb    = (USH*)(smem + 70656);     // [17][64] bf16
    USH* tapssb  = (USH*)(smem + 72832);     // [128][16] bf16 p values

    const USH* qp  = qb   + (size_t)bh * (S_LEN * DK);
    const USH* kp  = kbuf + (size_t)bh * (S_LEN * DK);
    const USH* vtp = vtg  + (size_t)bh * (S_LEN * DK);  // [d=64][s=1024]

    auto stage = [&](int j0, int slot) {
        const int o = t * 16;
        const int row = o >> 7;
        const int chunk = (o >> 4) & 7;
        const int sc = (chunk ^ (row & 7)) * 8;
        gload16(kp + (size_t)(j0 + row) * DK + sc, smem + slot * 8192 + o);
        gload16(vtp + (size_t)row * S_LEN + j0 + sc, smem + 24576 + slot * 8192 + o);
    };

    // ---- phase 0 ----
    stage(0, 0);
    for (int f = t; f < 2048; f += 512) {
        const int row = f >> 4, c4 = (f & 15) * 4;
        unsigned byte = ((unsigned)(row * 128 + c4 * 2)) ^ (((unsigned)row & 7) << 4);
        *(ushort4*)(qsb + byte) = *(const ushort4*)&qp[(size_t)(i0 + row) * DK + c4];
    }
    for (int e = t; e < 32 * 64; e += 512) {
        const int row = e >> 6, d = e & 63;
        const USH v = (row < 17) ? (USH)f2b(lut_k[row * 64 + d]) : (USH)0;
        unsigned byte = ((unsigned)(row * 128 + d * 2)) ^ (((unsigned)row & 7) << 4);
        *(USH*)(lutkb + byte) = v;
    }
    for (int e = t; e < 17 * 64; e += 512)
        lvfb[e] = (USH)f2b(lut_v[e]);
    __syncthreads();

    bf16x8 qa[2];
    {
        const int row = w * 16 + c;
        #pragma unroll
        for (int kh = 0; kh < 2; ++kh) {
            unsigned byte = ((unsigned)(row * 128 + kh * 64 + g * 16))
                          ^ (((unsigned)row & 7) << 4);
            qa[kh] = *(const bf16x8*)(qsb + byte);
        }
    }

    {
        f32x4 qr[2];
        qr[0] = (f32x4)0.f; qr[1] = (f32x4)0.f;
        #pragma unroll
        for (int sub2 = 0; sub2 < 2; ++sub2) {
            const int tap = sub2 * 16 + c;
            #pragma unroll
            for (int kh = 0; kh < 2; ++kh) {
                unsigned byte = ((unsigned)(tap * 128 + kh * 64 + g * 16))
                              ^ (((unsigned)tap & 7) << 4);
                bf16x8 lb = *(const bf16x8*)(lutkb + byte);
                qr[sub2] = __builtin_amdgcn_mfma_f32_16x16x32_bf16(
                    qa[kh], lb, qr[sub2], 0, 0, 0);
            }
        }
        #pragma unroll
        for (int sub2 = 0; sub2 < 2; ++sub2) {
            const int tap = sub2 * 16 + c;
            if (tap < 17) {
                #pragma unroll
                for (int r = 0; r < 4; ++r)
                    qrelb[(w * 16 + g * 4 + r) * 20 + tap] = (USH)f2b(qr[sub2][r]);
            }
        }
    }
    float qrel0s[4];
    #pragma unroll
    for (int r = 0; r < 4; ++r)
        qrel0s[r] = b2f(qrelb[(w * 16 + g * 4 + r) * 20]) * EXPSCALE;

    __syncthreads();

    const int NT = 2 * ib + 2;
    if (1 < NT) stage(64, 1);

    f32x4 acc[4];
    #pragma unroll
    for (int dt = 0; dt < 4; ++dt) acc[dt] = (f32x4)0.f;
    float l_r[4];
    #pragma unroll
    for (int r = 0; r < 4; ++r) l_r[r] = 0.f;

    const int wrow0 = i0 + w * 16;
    int cur = 0;
    for (int tile = 0; tile < NT; ++tile) {
        const int nxt2 = tile + 2;
        const int slot2 = (cur + 2 >= 3) ? cur - 1 : cur + 2;
        if (nxt2 < NT)
            stage(nxt2 << 6, slot2);

        if (tile * 64 > wrow0 + 15) {
            if (nxt2 < NT) asm volatile("s_waitcnt vmcnt(2)" ::: "memory");
            else           asm volatile("s_waitcnt vmcnt(0)" ::: "memory");
            __builtin_amdgcn_s_barrier();
            cur = (cur + 1 == 3) ? 0 : cur + 1;
            continue;
        }

        const char* ktb = smem + cur * 8192;
        const char* vtb = smem + 24576 + cur * 8192;

        float p[4][4];
        __builtin_amdgcn_s_setprio(1);
        f32x4 s[4];
        #pragma unroll
        for (int sub = 0; sub < 4; ++sub) {
            s[sub] = (f32x4)0.f;
            const int krow = sub * 16 + c;
            #pragma unroll
            for (int kh = 0; kh < 2; ++kh) {
                unsigned byte = ((unsigned)krow << 7) + ((unsigned)kh << 6) + ((unsigned)g << 4);
                byte ^= (unsigned)(krow & 7) << 4;
                bf16x8 kb = *(const bf16x8*)(ktb + byte);
                s[sub] = __builtin_amdgcn_mfma_f32_16x16x32_bf16(qa[kh], kb, s[sub], 0, 0, 0);
            }
        }
        __builtin_amdgcn_s_setprio(0);

        if (tile * 64 + 79 <= wrow0) {
            #pragma unroll
            for (int sub = 0; sub < 4; ++sub)
                #pragma unroll
                for (int r = 0; r < 4; ++r)
                    p[sub][r] = fast_exp2(s[sub][r] * EXPSCALE + qrel0s[r]);
        } else {
            #pragma unroll
            for (int sub = 0; sub < 4; ++sub) {
                const int dbase = tile * 64 + (sub * 16 + c) - i0 - (w * 16 + g * 4);
                #pragma unroll
                for (int r = 0; r < 4; ++r) {
                    const int dj = dbase - r;
                    int t17 = dj + 16;
                    t17 = t17 < 0 ? 0 : (t17 > 16 ? 16 : t17);
                    const int il = w * 16 + g * 4 + r;
                    float pv = fast_exp2((s[sub][r] + b2f(qrelb[il * 20 + t17])) * EXPSCALE);
                    if (dj > 0) pv = 0.f;
                    p[sub][r] = pv;
                    if (dj >= -15 && dj <= 0)
                        tapssb[il * 16 + dj + 15] = (USH)f2b(pv);
                }
            }
        }

        #pragma unroll
        for (int r = 0; r < 4; ++r)
            l_r[r] += (p[0][r] + p[1][r]) + (p[2][r] + p[3][r]);

        char* pw = pb + w * 2048;
        #pragma unroll
        for (int sub = 0; sub < 4; ++sub)
            #pragma unroll
            for (int r = 0; r < 4; ++r) {
                const int row = g * 4 + r;
                unsigned byte = ((unsigned)row << 7) + (((unsigned)(sub * 16 + c)) << 1);
                byte ^= (unsigned)(row & 7) << 4;
                *(short*)(pw + byte) = f2b(p[sub][r]);
            }

        bf16x8 pa[2];
        #pragma unroll
        for (int jh = 0; jh < 2; ++jh) {
            unsigned byte = ((unsigned)c << 7) + ((unsigned)jh << 6) + ((unsigned)g << 4);
            byte ^= (unsigned)(c & 7) << 4;
            pa[jh] = *(const bf16x8*)(pw + byte);
        }
        __builtin_amdgcn_s_setprio(1);
        #pragma unroll
        for (int dt = 0; dt < 4; ++dt) {
            const int d = dt * 16 + c;
            #pragma unroll
            for (int jh = 0; jh < 2; ++jh) {
                unsigned byte = ((unsigned)d << 7) + ((unsigned)jh << 6) + ((unsigned)g << 4);
                byte ^= (unsigned)(d & 7) << 4;
                bf16x8 vb = *(const bf16x8*)(vtb + byte);
                acc[dt] = __builtin_amdgcn_mfma_f32_16x16x32_bf16(pa[jh], vb, acc[dt], 0, 0, 0);
            }
        }
        __builtin_amdgcn_s_setprio(0);

        if (nxt2 < NT) asm volatile("s_waitcnt vmcnt(2)" ::: "memory");
        else           asm volatile("s_waitcnt vmcnt(0)" ::: "memory");
        __builtin_amdgcn_s_barrier();
        cur = (cur + 1 == 3) ? 0 : cur + 1;
    }

    const int rbase = w * 16 + g * 4;
    #pragma unroll
    for (int r = 0; r < 4; ++r) {
        float lsum = l_r[r];
        #pragma unroll
        for (int msk = 1; msk < 16; msk <<= 1)
            lsum += __shfl_xor(lsum, msk);
        const int il = rbase + r;
        float c0 = lsum;
        float tp[16];
        #pragma unroll
        for (int tap = 0; tap < 16; ++tap) {
            const int jg = i0 + il + tap - 15;
            const float pv = (jg >= 0) ? b2f(tapssb[il * 16 + tap]) : 0.f;
            tp[tap] = pv;
            c0 -= pv;
        }
        const float invl = 1.f / lsum;
        #pragma unroll
        for (int dt = 0; dt < 4; ++dt) {
            const int d = dt * 16 + c;
            float o = acc[dt][r] + c0 * b2f(lvfb[d]);
            #pragma unroll
            for (int tap = 0; tap < 16; ++tap)
                o += tp[tap] * b2f(lvfb[(tap + 1) * 64 + d]);
            o *= invl;
            ao[((size_t)b * S_LEN + (i0 + il)) * D_MODEL + h * DK + d] = (USH)f2b(o);
        }
    }
}

// ---------------------------------------------------------------------------
extern "C" void kernel_launch(void* const* d_in, const int* in_sizes, int n_in,
                              void* d_out, int out_size, void* d_ws, size_t ws_size,
                              hipStream_t stream) {
    const float* x      = (const float*)d_in[0];
    const float* W_attn = (const float*)d_in[1];
    const float* b_attn = (const float*)d_in[2];
    const float* W_proj = (const float*)d_in[3];
    const float* b_proj = (const float*)d_in[4];
    const float* lut_k  = (const float*)d_in[5];
    const float* lut_v  = (const float*)d_in[6];
    float* out = (float*)d_out;

    // workspace layout (all USH)
    USH* qb    = (USH*)d_ws;            // 8M
    USH* kb    = qb + HSZ;              // 8M
    USH* vb    = kb + HSZ;              // 8M (unused)
    USH* vtg   = vb + HSZ;              // 8M (per-head transposed V, from GEMM)
    USH* aob   = vtg + HSZ;             // 8M
    USH* xb    = aob + HSZ;             // 8M
    USH* watt  = xb + HSZ;              // 3M
    USH* wproj = watt + 3145728;        // 1M

    // 0) fused prep: x->bf16, W_attn^T, W_proj^T
    prep_kernel<<<5120, 256, 0, stream>>>(x, xb, W_attn, watt, W_proj, wproj);

    // 1) QKV projection (256x128 tri-buffered, V written transposed in-kernel)
    gemm256_kernel<1><<<768, 512, 0, stream>>>(
        xb, watt, b_attn, nullptr, qb, kb, vtg, 3072, 24);

    // 2) attention
    attn_mfma_kernel<<<1024, 512, 0, stream>>>(qb, kb, vtg, lut_k, lut_v, aob);

    // 3) output projection (256x128 tri-buffered, fp32 out)
    gemm256_kernel<0><<<256, 512, 0, stream>>>(
        aob, wproj, b_proj, out, nullptr, nullptr, nullptr, 1024, 8);
}

// Round 17
// 173.024 us; speedup vs baseline: 1.2188x; 1.0343x over previous
//
#include <hip/hip_runtime.h>
#include <hip/hip_bf16.h>
#include <math.h>

#define NH 16
#define S_LEN 1024
#define DK 64
#define D_MODEL 1024
#define HSZ 8388608          // B*NH*S*DK elements per q/k/v buffer

typedef __attribute__((ext_vector_type(8))) short bf16x8;
typedef __attribute__((ext_vector_type(4))) float f32x4;
typedef unsigned short USH;

#define EXPSCALE 0.1803368801111204f   // 0.125 * log2(e)

__device__ __forceinline__ float fast_exp2(float x) {
    return __builtin_amdgcn_exp2f(x);
}

__device__ __forceinline__ short f2b(float x) {
    union { __hip_bfloat16 h; short s; } u;
    u.h = __float2bfloat16(x);
    return u.s;
}
__device__ __forceinline__ float b2f(USH u) {
    union { unsigned i; float f; } x;
    x.i = (unsigned)u << 16;
    return x.f;
}

__device__ __forceinline__ void gload16(const void* src, void* lds) {
    __builtin_amdgcn_global_load_lds(
        (const __attribute__((address_space(1))) void*)src,
        (__attribute__((address_space(3))) void*)lds,
        16, 0, 0);
}

// ---------------------------------------------------------------------------
// Fused prep: fp32->bf16 conv of x  +  transpose-convert of W_attn, W_proj.
// ---------------------------------------------------------------------------
__global__ __launch_bounds__(256)
void prep_kernel(const float* __restrict__ x, USH* __restrict__ xb,
                 const float* __restrict__ W_attn, USH* __restrict__ watt,
                 const float* __restrict__ W_proj, USH* __restrict__ wproj) {
    const int blk = blockIdx.x;
    const int t = threadIdx.x;
    if (blk < 4096) {
        const int i = (blk * 256 + t) * 8;
        const float4 a = *(const float4*)&x[i];
        const float4 b = *(const float4*)&x[i + 4];
        ushort4 o0, o1;
        o0.x = (USH)f2b(a.x); o0.y = (USH)f2b(a.y); o0.z = (USH)f2b(a.z); o0.w = (USH)f2b(a.w);
        o1.x = (USH)f2b(b.x); o1.y = (USH)f2b(b.y); o1.z = (USH)f2b(b.z); o1.w = (USH)f2b(b.w);
        *(ushort4*)&xb[i] = o0;
        *(ushort4*)&xb[i + 4] = o1;
        return;
    }
    __shared__ USH Ts[64][65];
    const float* in;
    USH* out;
    int R, C, r0, c0;
    if (blk < 4864) {
        const int idx = blk - 4096;
        in = W_attn; out = watt; R = 1024; C = 3072;
        c0 = (idx % 48) * 64; r0 = (idx / 48) * 64;
    } else {
        const int idx = blk - 4864;
        in = W_proj; out = wproj; R = 1024; C = 1024;
        c0 = (idx % 16) * 64; r0 = (idx / 16) * 64;
    }
    const int tr = t >> 4;
    const int tc4 = (t & 15) * 4;
    #pragma unroll
    for (int ph = 0; ph < 4; ++ph) {
        const int r = ph * 16 + tr;
        const float4 v = *(const float4*)&in[(size_t)(r0 + r) * C + c0 + tc4];
        Ts[tc4 + 0][r] = (USH)f2b(v.x);
        Ts[tc4 + 1][r] = (USH)f2b(v.y);
        Ts[tc4 + 2][r] = (USH)f2b(v.z);
        Ts[tc4 + 3][r] = (USH)f2b(v.w);
    }
    __syncthreads();
    #pragma unroll
    for (int ph = 0; ph < 4; ++ph) {
        const int cc = ph * 16 + tr;
        ushort4 o;
        o.x = Ts[cc][tc4 + 0]; o.y = Ts[cc][tc4 + 1];
        o.z = Ts[cc][tc4 + 2]; o.w = Ts[cc][tc4 + 3];
        *(ushort4*)&out[(size_t)(c0 + cc) * R + r0 + tc4] = o;
    }
}

// ---------------------------------------------------------------------------
// 256x128-tile GEMM, BK=32, 512 thr (8 waves 4Mx2N), tri-buffered counted-
// vmcnt pipeline. QKV=1: V n-tiles written transposed via in-LDS transpose.
// ---------------------------------------------------------------------------
template<int QKV>
__global__ __launch_bounds__(512)
void gemm256_kernel(const USH* __restrict__ A, const USH* __restrict__ Bt,
                    const float* __restrict__ bias,
                    float* __restrict__ Cf, USH* __restrict__ Cq,
                    USH* __restrict__ Ck, USH* __restrict__ Cvt,
                    int N, int NTILN) {
    __shared__ __align__(16) USH lds[36864];   // 72 KB
    const int t = threadIdx.x;
    const int w = t >> 6, lane = t & 63, g = lane >> 4, c = lane & 15;
    const int wm = w >> 1, wn = w & 1;         // 4M x 2N waves
    const int nwg = NTILN * 32;
    const int bid = blockIdx.x;
    const int swz = (bid & 7) * (nwg >> 3) + (bid >> 3);   // nwg%8==0 bijective
    const int bn0 = (swz % NTILN) * 128;
    const int bm0 = (swz / NTILN) * 256;

    auto stage = [&](int kt, int slot) {
        const int k0 = kt * 32;
        char* base = (char*)lds + slot * 24576;
        #pragma unroll
        for (int q = 0; q < 2; ++q) {
            const int o = t * 16 + q * 8192;
            const int row = o >> 6;
            const int sc = (((o >> 4) & 3) ^ (row & 3)) * 8;
            gload16(A + (size_t)(bm0 + row) * 1024 + k0 + sc, base + o);
        }
        const int o = t * 16;
        const int row = o >> 6;
        const int sc = (((o >> 4) & 3) ^ (row & 3)) * 8;
        gload16(Bt + (size_t)(bn0 + row) * 1024 + k0 + sc, base + 16384 + o);
    };

    unsigned aoff[4], boff[4];
    #pragma unroll
    for (int i = 0; i < 4; ++i) {
        const int row = wm * 64 + i * 16 + c;
        aoff[i] = (unsigned)(row * 64) + (((unsigned)(g ^ (row & 3))) << 4);
        const int rn = wn * 64 + i * 16 + c;
        boff[i] = 16384u + (unsigned)(rn * 64) + (((unsigned)(g ^ (rn & 3))) << 4);
    }

    f32x4 acc[4][4];
    #pragma unroll
    for (int i = 0; i < 4; ++i)
        #pragma unroll
        for (int j = 0; j < 4; ++j) acc[i][j] = (f32x4)0.f;

    stage(0, 0);
    stage(1, 1);

    int cur = 0;
    for (int kt = 0; kt < 32; ++kt) {
        if (kt < 31) asm volatile("s_waitcnt vmcnt(3)" ::: "memory");
        else         asm volatile("s_waitcnt vmcnt(0)" ::: "memory");
        __builtin_amdgcn_s_barrier();

        const int slot2 = (cur + 2 >= 3) ? cur - 1 : cur + 2;
        if (kt + 2 < 32)
            stage(kt + 2, slot2);

        const char* sb = (const char*)lds + cur * 24576;
        bf16x8 af[4], bfr[4];
        #pragma unroll
        for (int i = 0; i < 4; ++i) af[i] = *(const bf16x8*)(sb + aoff[i]);
        #pragma unroll
        for (int j = 0; j < 4; ++j) bfr[j] = *(const bf16x8*)(sb + boff[j]);

        __builtin_amdgcn_s_setprio(1);
        #pragma unroll
        for (int i = 0; i < 4; ++i)
            #pragma unroll
            for (int j = 0; j < 4; ++j)
                acc[i][j] = __builtin_amdgcn_mfma_f32_16x16x32_bf16(
                    af[i], bfr[j], acc[i][j], 0, 0, 0);
        __builtin_amdgcn_s_setprio(0);

        cur = (cur + 1 == 3) ? 0 : cur + 1;
    }

    if (QKV) {
        if (bn0 < 2048) {
            #pragma unroll
            for (int i = 0; i < 4; ++i) {
                #pragma unroll
                for (int reg = 0; reg < 4; ++reg) {
                    const int m = bm0 + wm * 64 + i * 16 + g * 4 + reg;
                    const int b = m >> 10, s = m & 1023;
                    #pragma unroll
                    for (int j = 0; j < 4; ++j) {
                        const int n = bn0 + wn * 64 + j * 16 + c;
                        const float v = acc[i][j][reg] + bias[n];
                        const int which = n >> 10;
                        const int h = (n & 1023) >> 6, d = n & 63;
                        const size_t idx = (((size_t)(b * NH + h)) * S_LEN + s) * DK + d;
                        if (which == 0) Cq[idx] = (USH)f2b(v);
                        else            Ck[idx] = (USH)f2b(v);
                    }
                }
            }
        } else {
            __syncthreads();
            #pragma unroll
            for (int i = 0; i < 4; ++i) {
                const int m_local = wm * 64 + i * 16 + g * 4;
                #pragma unroll
                for (int j = 0; j < 4; ++j) {
                    const int n_local = wn * 64 + j * 16 + c;
                    const int n = bn0 + n_local;
                    ushort4 pk;
                    pk.x = (USH)f2b(acc[i][j][0] + bias[n]);
                    pk.y = (USH)f2b(acc[i][j][1] + bias[n]);
                    pk.z = (USH)f2b(acc[i][j][2] + bias[n]);
                    pk.w = (USH)f2b(acc[i][j][3] + bias[n]);
                    unsigned byte = ((unsigned)(n_local * 512 + m_local * 2))
                                  ^ (((unsigned)n_local & 7) << 4);
                    *(ushort4*)((char*)lds + byte) = pk;
                }
            }
            __syncthreads();
            const int b = bm0 >> 10, s0 = bm0 & 1023;
            const int h0 = (bn0 & 1023) >> 6;
            #pragma unroll
            for (int e = 0; e < 8; ++e) {
                const int task = e * 512 + t;
                const int n_local = task >> 5;
                const int chunk = task & 31;
                unsigned byte = ((unsigned)(n_local * 512 + chunk * 16))
                              ^ (((unsigned)n_local & 7) << 4);
                bf16x8 v = *(const bf16x8*)((char*)lds + byte);
                const int h = h0 + (n_local >> 6);
                const int d = n_local & 63;
                *(bf16x8*)&Cvt[(((size_t)(b * NH + h)) * DK + d) * S_LEN
                               + s0 + chunk * 8] = v;
            }
        }
    } else {
        #pragma unroll
        for (int i = 0; i < 4; ++i) {
            #pragma unroll
            for (int reg = 0; reg < 4; ++reg) {
                const int m = bm0 + wm * 64 + i * 16 + g * 4 + reg;
                #pragma unroll
                for (int j = 0; j < 4; ++j) {
                    const int n = bn0 + wn * 64 + j * 16 + c;
                    Cf[(size_t)m * N + n] = acc[i][j][reg] + bias[n];
                }
            }
        }
    }
}

// ---------------------------------------------------------------------------
// MFMA flash attention with SWAPPED QK^T: s = mfma(K, Q) yields S^T, so each
// lane holds P[q = w*16+c][k = tile*64+sub*16+g*4+r] — k-contiguous in r.
// P-write: 4 x ds_write_b64 (vs 16 x ds_write_b16). P-read/PV/acc unchanged.
// Row q is lane-uniform: scalar qrel0, scalar row-sum (reduced via 2 shfls +
// per-wave LDS redistribution for the epilogue).
// ---------------------------------------------------------------------------
__global__ __launch_bounds__(512, 4)
void attn_mfma_kernel(const USH* __restrict__ qb,
                      const USH* __restrict__ kbuf,
                      const USH* __restrict__ vtg,
                      const float* __restrict__ lut_k,
                      const float* __restrict__ lut_v,
                      USH* __restrict__ ao) {
    const int bid = blockIdx.x;
    const int logical = (bid & 7) * 128 + (bid >> 3);   // XCD-contiguous bh
    const int ib = 7 - (logical & 7);                   // LPT: big ib first
    const int bh = logical >> 3;
    const int b = bh >> 4, h = bh & 15;
    const int i0 = ib * 128;
    const int t = threadIdx.x;
    const int w = t >> 6;          // 0..7
    const int lane = t & 63;
    const int g = lane >> 4;
    const int c = lane & 15;

    __shared__ __align__(16) char smem[77440];
    char* pb     = smem + 49152;             // P buffers (main loop)
    char* qsb    = smem + 49152;             // phase0 alias: q [128][64] swz
    char* lutkb  = smem + 8192;              // phase0 alias of ktb1
    USH* qrelb   = (USH*)(smem + 65536);     // [128][20] bf16
    USH* lvfb    = (USH*)(smem + 70656);     // [17][64] bf16
    USH* tapssb  = (USH*)(smem + 72832);     // [128][16] bf16 p values
    float* lsumb = (float*)(smem + 76928);   // [128] row sums

    const USH* qp  = qb   + (size_t)bh * (S_LEN * DK);
    const USH* kp  = kbuf + (size_t)bh * (S_LEN * DK);
    const USH* vtp = vtg  + (size_t)bh * (S_LEN * DK);  // [d=64][s=1024]

    auto stage = [&](int j0, int slot) {
        const int o = t * 16;
        const int row = o >> 7;
        const int chunk = (o >> 4) & 7;
        const int sc = (chunk ^ (row & 7)) * 8;
        gload16(kp + (size_t)(j0 + row) * DK + sc, smem + slot * 8192 + o);
        gload16(vtp + (size_t)row * S_LEN + j0 + sc, smem + 24576 + slot * 8192 + o);
    };

    // ---- phase 0 ----
    stage(0, 0);
    for (int f = t; f < 2048; f += 512) {
        const int row = f >> 4, c4 = (f & 15) * 4;
        unsigned byte = ((unsigned)(row * 128 + c4 * 2)) ^ (((unsigned)row & 7) << 4);
        *(ushort4*)(qsb + byte) = *(const ushort4*)&qp[(size_t)(i0 + row) * DK + c4];
    }
    for (int e = t; e < 32 * 64; e += 512) {
        const int row = e >> 6, d = e & 63;
        const USH v = (row < 17) ? (USH)f2b(lut_k[row * 64 + d]) : (USH)0;
        unsigned byte = ((unsigned)(row * 128 + d * 2)) ^ (((unsigned)row & 7) << 4);
        *(USH*)(lutkb + byte) = v;
    }
    for (int e = t; e < 17 * 64; e += 512)
        lvfb[e] = (USH)f2b(lut_v[e]);
    __syncthreads();

    bf16x8 qa[2];
    {
        const int row = w * 16 + c;
        #pragma unroll
        for (int kh = 0; kh < 2; ++kh) {
            unsigned byte = ((unsigned)(row * 128 + kh * 64 + g * 16))
                          ^ (((unsigned)row & 7) << 4);
            qa[kh] = *(const bf16x8*)(qsb + byte);
        }
    }

    {
        f32x4 qr[2];
        qr[0] = (f32x4)0.f; qr[1] = (f32x4)0.f;
        #pragma unroll
        for (int sub2 = 0; sub2 < 2; ++sub2) {
            const int tap = sub2 * 16 + c;
            #pragma unroll
            for (int kh = 0; kh < 2; ++kh) {
                unsigned byte = ((unsigned)(tap * 128 + kh * 64 + g * 16))
                              ^ (((unsigned)tap & 7) << 4);
                bf16x8 lb = *(const bf16x8*)(lutkb + byte);
                qr[sub2] = __builtin_amdgcn_mfma_f32_16x16x32_bf16(
                    qa[kh], lb, qr[sub2], 0, 0, 0);
            }
        }
        #pragma unroll
        for (int sub2 = 0; sub2 < 2; ++sub2) {
            const int tap = sub2 * 16 + c;
            if (tap < 17) {
                #pragma unroll
                for (int r = 0; r < 4; ++r)
                    qrelb[(w * 16 + g * 4 + r) * 20 + tap] = (USH)f2b(qr[sub2][r]);
            }
        }
    }
    __syncthreads();   // qsb/lutkb reads done; overlay safe; qrelb visible

    const int il = w * 16 + c;         // this lane's q-row (swapped layout)
    const float qrel0s = b2f(qrelb[il * 20]) * EXPSCALE;

    const int NT = 2 * ib + 2;
    if (1 < NT) stage(64, 1);

    f32x4 acc[4];
    #pragma unroll
    for (int dt = 0; dt < 4; ++dt) acc[dt] = (f32x4)0.f;
    float l_r = 0.f;                   // per-lane partial sum for row il

    const int wrow0 = i0 + w * 16;
    int cur = 0;
    for (int tile = 0; tile < NT; ++tile) {
        const int nxt2 = tile + 2;
        const int slot2 = (cur + 2 >= 3) ? cur - 1 : cur + 2;
        if (nxt2 < NT)
            stage(nxt2 << 6, slot2);

        if (tile * 64 > wrow0 + 15) {
            if (nxt2 < NT) asm volatile("s_waitcnt vmcnt(2)" ::: "memory");
            else           asm volatile("s_waitcnt vmcnt(0)" ::: "memory");
            __builtin_amdgcn_s_barrier();
            cur = (cur + 1 == 3) ? 0 : cur + 1;
            continue;
        }

        const char* ktb = smem + cur * 8192;
        const char* vtb = smem + 24576 + cur * 8192;

        // ---- swapped QK^T: s[sub] = K_sub x Q^T  (S^T fragments) ----
        float p[4][4];
        __builtin_amdgcn_s_setprio(1);
        f32x4 s[4];
        #pragma unroll
        for (int sub = 0; sub < 4; ++sub) {
            s[sub] = (f32x4)0.f;
            const int krow = sub * 16 + c;
            #pragma unroll
            for (int kh = 0; kh < 2; ++kh) {
                unsigned byte = ((unsigned)krow << 7) + ((unsigned)kh << 6) + ((unsigned)g << 4);
                byte ^= (unsigned)(krow & 7) << 4;
                bf16x8 kb = *(const bf16x8*)(ktb + byte);
                s[sub] = __builtin_amdgcn_mfma_f32_16x16x32_bf16(kb, qa[kh], s[sub], 0, 0, 0);
            }
        }
        __builtin_amdgcn_s_setprio(0);

        if (tile * 64 + 79 <= wrow0) {
            #pragma unroll
            for (int sub = 0; sub < 4; ++sub)
                #pragma unroll
                for (int r = 0; r < 4; ++r)
                    p[sub][r] = fast_exp2(s[sub][r] * EXPSCALE + qrel0s);
        } else {
            #pragma unroll
            for (int sub = 0; sub < 4; ++sub) {
                const int jbase = tile * 64 + sub * 16 + g * 4;
                #pragma unroll
                for (int r = 0; r < 4; ++r) {
                    const int dj = jbase + r - (i0 + il);
                    int t17 = dj + 16;
                    t17 = t17 < 0 ? 0 : (t17 > 16 ? 16 : t17);
                    float pv = fast_exp2((s[sub][r] + b2f(qrelb[il * 20 + t17])) * EXPSCALE);
                    if (dj > 0) pv = 0.f;
                    p[sub][r] = pv;
                    if (dj >= -15 && dj <= 0)
                        tapssb[il * 16 + dj + 15] = (USH)f2b(pv);
                }
            }
        }

        #pragma unroll
        for (int sub = 0; sub < 4; ++sub)
            l_r += (p[sub][0] + p[sub][1]) + (p[sub][2] + p[sub][3]);

        // ---- P -> per-wave LDS: 4 x ds_write_b64, row = il (q) ----
        char* pw = pb + w * 2048;
        #pragma unroll
        for (int sub = 0; sub < 4; ++sub) {
            const unsigned u0 = ((unsigned)(USH)f2b(p[sub][1]) << 16)
                              | (unsigned)(USH)f2b(p[sub][0]);
            const unsigned u1 = ((unsigned)(USH)f2b(p[sub][3]) << 16)
                              | (unsigned)(USH)f2b(p[sub][2]);
            uint2 val; val.x = u0; val.y = u1;
            unsigned byte = ((unsigned)(c * 128 + sub * 32 + g * 8))
                          ^ (((unsigned)c & 7) << 4);
            *(uint2*)(pw + byte) = val;
        }

        // ---- PV (unchanged: A=P from LDS, B=V^T) ----
        bf16x8 pa[2];
        #pragma unroll
        for (int jh = 0; jh < 2; ++jh) {
            unsigned byte = ((unsigned)c << 7) + ((unsigned)jh << 6) + ((unsigned)g << 4);
            byte ^= (unsigned)(c & 7) << 4;
            pa[jh] = *(const bf16x8*)(pw + byte);
        }
        __builtin_amdgcn_s_setprio(1);
        #pragma unroll
        for (int dt = 0; dt < 4; ++dt) {
            const int d = dt * 16 + c;
            #pragma unroll
            for (int jh = 0; jh < 2; ++jh) {
                unsigned byte = ((unsigned)d << 7) + ((unsigned)jh << 6) + ((unsigned)g << 4);
                byte ^= (unsigned)(d & 7) << 4;
                bf16x8 vb = *(const bf16x8*)(vtb + byte);
                acc[dt] = __builtin_amdgcn_mfma_f32_16x16x32_bf16(pa[jh], vb, acc[dt], 0, 0, 0);
            }
        }
        __builtin_amdgcn_s_setprio(0);

        if (nxt2 < NT) asm volatile("s_waitcnt vmcnt(2)" ::: "memory");
        else           asm volatile("s_waitcnt vmcnt(0)" ::: "memory");
        __builtin_amdgcn_s_barrier();
        cur = (cur + 1 == 3) ? 0 : cur + 1;
    }

    // ---- reduce row sum for row il (lanes c, c+16, c+32, c+48) ----
    float lsum = l_r;
    lsum += __shfl_xor(lsum, 16);
    lsum += __shfl_xor(lsum, 32);
    if (g == 0) lsumb[il] = lsum;      // same-wave DS order covers the read

    // ---- epilogue (acc rows = w*16 + g*4 + r, cols = dt*16 + c) ----
    const int rbase = w * 16 + g * 4;
    #pragma unroll
    for (int r = 0; r < 4; ++r) {
        const int ilr = rbase + r;
        const float lsr = lsumb[w * 16 + g * 4 + r];
        float c0 = lsr;
        float tp[16];
        #pragma unroll
        for (int tap = 0; tap < 16; ++tap) {
            const int jg = i0 + ilr + tap - 15;
            const float pv = (jg >= 0) ? b2f(tapssb[ilr * 16 + tap]) : 0.f;
            tp[tap] = pv;
            c0 -= pv;
        }
        const float invl = 1.f / lsr;
        #pragma unroll
        for (int dt = 0; dt < 4; ++dt) {
            const int d = dt * 16 + c;
            float o = acc[dt][r] + c0 * b2f(lvfb[d]);
            #pragma unroll
            for (int tap = 0; tap < 16; ++tap)
                o += tp[tap] * b2f(lvfb[(tap + 1) * 64 + d]);
            o *= invl;
            ao[((size_t)b * S_LEN + (i0 + ilr)) * D_MODEL + h * DK + d] = (USH)f2b(o);
        }
    }
}

// ---------------------------------------------------------------------------
extern "C" void kernel_launch(void* const* d_in, const int* in_sizes, int n_in,
                              void* d_out, int out_size, void* d_ws, size_t ws_size,
                              hipStream_t stream) {
    const float* x      = (const float*)d_in[0];
    const float* W_attn = (const float*)d_in[1];
    const float* b_attn = (const float*)d_in[2];
    const float* W_proj = (const float*)d_in[3];
    const float* b_proj = (const float*)d_in[4];
    const float* lut_k  = (const float*)d_in[5];
    const float* lut_v  = (const float*)d_in[6];
    float* out = (float*)d_out;

    // workspace layout (all USH)
    USH* qb    = (USH*)d_ws;            // 8M
    USH* kb    = qb + HSZ;              // 8M
    USH* vb    = kb + HSZ;              // 8M (unused)
    USH* vtg   = vb + HSZ;              // 8M (per-head transposed V, from GEMM)
    USH* aob   = vtg + HSZ;             // 8M
    USH* xb    = aob + HSZ;             // 8M
    USH* watt  = xb + HSZ;              // 3M
    USH* wproj = watt + 3145728;        // 1M

    // 0) fused prep: x->bf16, W_attn^T, W_proj^T
    prep_kernel<<<5120, 256, 0, stream>>>(x, xb, W_attn, watt, W_proj, wproj);

    // 1) QKV projection (256x128 tri-buffered, V written transposed in-kernel)
    gemm256_kernel<1><<<768, 512, 0, stream>>>(
        xb, watt, b_attn, nullptr, qb, kb, vtg, 3072, 24);

    // 2) attention (swapped-QK^T P path)
    attn_mfma_kernel<<<1024, 512, 0, stream>>>(qb, kb, vtg, lut_k, lut_v, aob);

    // 3) output projection (256x128 tri-buffered, fp32 out)
    gemm256_kernel<0><<<256, 512, 0, stream>>>(
        aob, wproj, b_proj, out, nullptr, nullptr, nullptr, 1024, 8);
}